// Round 4
// baseline (7693.316 us; speedup 1.0000x reference)
//
#include <hip/hip_runtime.h>
#include <cstdint>
#include <cstddef>

#define BB 64
#define NN 512
#define DD 768
#define KB 64
#define NSTEP (NN/KB)

typedef __bf16 bf16x8 __attribute__((ext_vector_type(8)));
typedef float f32x4 __attribute__((ext_vector_type(4)));
typedef unsigned short us8 __attribute__((ext_vector_type(8)));
typedef double f64x4 __attribute__((ext_vector_type(4)));
typedef double f64x2 __attribute__((ext_vector_type(2)));

__device__ __forceinline__ float aval(float adjv, float mi, float mj) {
    return expf(fmaxf(adjv - 50.f * (mi + mj), -40.f));
}

__device__ __forceinline__ unsigned short f2bf(float v) {
    union { float f; unsigned int u; } c; c.f = v;
    return (unsigned short)((c.u + 0x7fffu + ((c.u >> 16) & 1u)) >> 16);
}
__device__ __forceinline__ float bf2f(unsigned short h) {
    union { unsigned int u; float f; } c; c.u = ((unsigned int)h) << 16;
    return c.f;
}

__device__ __forceinline__ void gl_lds16(const void* g, void* l) {
    __builtin_amdgcn_global_load_lds((const __attribute__((address_space(1))) unsigned int*)g,
                                     (__attribute__((address_space(3))) unsigned int*)l, 16, 0, 0);
}

// ---------------- root / R ----------------
__global__ void k_root(const float* __restrict__ x, const float* __restrict__ mask,
                       const float* __restrict__ w, const float* __restrict__ br,
                       float* __restrict__ R) {
    int wave = threadIdx.x >> 6, lane = threadIdx.x & 63;
    int row = blockIdx.x * 4 + wave;
    const float* xr = x + (size_t)row * DD;
    float s = 0.f;
#pragma unroll
    for (int k = 0; k < DD / 64; ++k) s += xr[k * 64 + lane] * w[k * 64 + lane];
    for (int off = 32; off; off >>= 1) s += __shfl_down(s, off, 64);
    if (lane == 0) {
        float m = mask[row] * -1e-4f;
        float rv = fmaxf(s + br[0] - 50.f * m, -40.f);
        R[row] = expf(rv);
    }
}

// ---------------- column sums of A (partials) ----------------
__global__ void k_colsum(const float* __restrict__ adj, const float* __restrict__ mask,
                         double* __restrict__ Lp) {
    int b = blockIdx.x, chunk = blockIdx.y;
    int j = threadIdx.x;
    float mj = mask[b * NN + j] * -1e-4f;
    const float* ab = adj + (size_t)b * NN * NN;
    double acc = 0.0;
    int i0 = chunk * 128;
    for (int i = i0; i < i0 + 128; ++i) {
        float mi = mask[b * NN + i] * -1e-4f;
        acc += (double)aval(ab[(size_t)i * NN + j], mi, mj);
    }
    Lp[((size_t)b * 4 + chunk) * NN + j] = acc;
}

// ---------------- build LL ----------------
template <typename T>
__global__ void k_build(const float* __restrict__ adj, const float* __restrict__ mask,
                        const float* __restrict__ R, const double* __restrict__ Lp,
                        T* __restrict__ M) {
    int b = blockIdx.x >> 9;
    int r = blockIdx.x & 511;
    int c = threadIdx.x;
    float mr = mask[b * NN + r] * -1e-4f;
    float mc = mask[b * NN + c] * -1e-4f;
    size_t idx = ((size_t)b * NN + r) * NN + c;
    float a = aval(adj[idx], mr, mc);
    T v;
    if (r == c) {
        const double* lp = Lp + (size_t)b * 4 * NN;
        double L = lp[c] + lp[NN + c] + lp[2 * NN + c] + lp[3 * NN + c];
        v = (T)(L - (double)a + (double)R[b * NN + c]);
    } else {
        v = (T)(-a);
    }
    M[idx] = v;
}

// ---------------- save column panel ----------------
template <typename T>
__global__ void k_savecol(const T* __restrict__ M, T* __restrict__ Cb, int k0) {
    int t = threadIdx.x;
    int c = t & 63, rr = t >> 6;
    int row = blockIdx.x * 4 + rr;
    int b = row >> 9, i = row & 511;
    Cb[(size_t)row * KB + c] = M[((size_t)b * NN + i) * NN + k0 + c];
}

// ---------------- invert 64x64 pivot block ----------------
template <typename T>
__global__ void k_invblk(const T* __restrict__ M, T* __restrict__ Bb, int k0) {
    __shared__ double pr[KB];
    __shared__ double fv[KB];
    __shared__ double pvt;
    int b = blockIdx.x;
    int r = threadIdx.x & 63, q = threadIdx.x >> 6;
    double a[16];
    const T* Mb = M + ((size_t)b * NN + k0) * NN + k0;
#pragma unroll
    for (int c = 0; c < 16; ++c) a[c] = (double)Mb[(size_t)r * NN + q * 16 + c];
    for (int k = 0; k < KB; ++k) {
        int kq = k >> 4, kc = k & 15;
        if (r == k && q == kq) pvt = a[kc];
        __syncthreads();
        double ip = 1.0 / pvt;
        if (r == k) {
#pragma unroll
            for (int c = 0; c < 16; ++c) a[c] *= ip;
            if (q == kq) a[kc] = ip;
#pragma unroll
            for (int c = 0; c < 16; ++c) pr[q * 16 + c] = a[c];
        }
        if (r != k && q == kq) fv[r] = a[kc];
        __syncthreads();
        if (r != k) {
            double f = fv[r];
#pragma unroll
            for (int c = 0; c < 16; ++c) a[c] -= f * pr[q * 16 + c];
            if (q == kq) a[kc] = -f * ip;
        }
        __syncthreads();
    }
    T* Bo = Bb + (size_t)b * KB * KB;
#pragma unroll
    for (int c = 0; c < 16; ++c) Bo[r * KB + q * 16 + c] = (T)a[c];
}

// ---------------- MFMA pivot rows (under test) ----------------
__global__ __launch_bounds__(256) void k_piv_mfma(double* __restrict__ M,
                                                  const double* __restrict__ Bb, int step) {
    __shared__ double Ms[64][66];
    int b = blockIdx.y, jt = blockIdx.x;
    int t = threadIdx.x, w = t >> 6, l = t & 63;
    double* Mb = M + (size_t)b * NN * NN;
    double* Pr = Mb + (size_t)(step * 64) * NN;
    const double* Bi = Bb + (size_t)b * KB * KB;
    if (jt == step) {
        for (int i = 0; i < 16; ++i) {
            int c = i * 256 + t;
            int row = c >> 6, col = c & 63;
            Pr[(size_t)row * NN + step * 64 + col] = Bi[row * 64 + col];
        }
        return;
    }
    const double* Mg = Pr + jt * 64;
    for (int i = 0; i < 8; ++i) {
        int c = i * 256 + t;
        int row = c >> 5, ch = c & 31;
        f64x2 v = *(const f64x2*)(Mg + (size_t)row * NN + ch * 2);
        Ms[row][ch * 2] = v[0]; Ms[row][ch * 2 + 1] = v[1];
    }
    __syncthreads();
    int lr = l & 15, lg = l >> 4;
    double a[16];
#pragma unroll
    for (int kk = 0; kk < 16; ++kk) a[kk] = Bi[(w * 16 + lr) * 64 + kk * 4 + lg];
    double* Og = Pr + (size_t)(w * 16) * NN + jt * 64;
#pragma unroll
    for (int cf = 0; cf < 4; ++cf) {
        f64x4 acc = {0., 0., 0., 0.};
#pragma unroll
        for (int kk = 0; kk < 16; ++kk)
            acc = __builtin_amdgcn_mfma_f64_16x16x4f64(a[kk], Ms[kk * 4 + lg][cf * 16 + lr], acc, 0, 0, 0);
#pragma unroll
        for (int r = 0; r < 4; ++r) Og[(size_t)(lg * 4 + r) * NN + cf * 16 + lr] = acc[r];
    }
}

// ---------------- MFMA rank-64 update (under test) ----------------
template <int COLMODE>
__global__ __launch_bounds__(256) void k_upd_mfma(double* __restrict__ M, int step) {
    __shared__ double Cs[64][66];
    int b = blockIdx.y;
    int x = blockIdx.x;
    int it, jt;
    if (COLMODE) { it = x; jt = step; }
    else { it = x / 7; jt = x % 7; if (jt >= step) ++jt; }
    if (it >= step) ++it;
    int t = threadIdx.x, w = t >> 6, l = t & 63;
    double* Mb = M + (size_t)b * NN * NN;
    {
        const double* Cg = Mb + (size_t)(it * 64) * NN + step * 64;
        for (int i = 0; i < 8; ++i) {
            int c = i * 256 + t;
            int row = c >> 5, ch = c & 31;
            f64x2 v = *(const f64x2*)(Cg + (size_t)row * NN + ch * 2);
            Cs[row][ch * 2] = -v[0]; Cs[row][ch * 2 + 1] = -v[1];
        }
    }
    __syncthreads();
    int lr = l & 15, lg = l >> 4;
    double a[16];
#pragma unroll
    for (int kk = 0; kk < 16; ++kk) a[kk] = Cs[w * 16 + lr][kk * 4 + lg];
    const double* Rg = Mb + (size_t)(step * 64) * NN + jt * 64;
    double* Og = Mb + (size_t)(it * 64 + w * 16) * NN + jt * 64;
#pragma unroll
    for (int cf = 0; cf < 4; ++cf) {
        int c0 = cf * 16 + lr;
        f64x4 acc;
        if (COLMODE) {
            acc = (f64x4){0., 0., 0., 0.};
        } else {
#pragma unroll
            for (int r = 0; r < 4; ++r) acc[r] = Og[(size_t)(lg * 4 + r) * NN + c0];
        }
        const double* bp = Rg + (size_t)lg * NN + c0;
#pragma unroll
        for (int kk = 0; kk < 16; ++kk) {
            double bv = bp[(size_t)(kk * 4) * NN];
            acc = __builtin_amdgcn_mfma_f64_16x16x4f64(a[kk], bv, acc, 0, 0, 0);
        }
#pragma unroll
        for (int r = 0; r < 4; ++r) Og[(size_t)(lg * 4 + r) * NN + c0] = acc[r];
    }
}

// ---------------- scalar pivrows / update (production path) ----------------
template <typename T>
__global__ void k_pivrows(T* __restrict__ M, const T* __restrict__ Bb, int k0) {
    __shared__ double Bi[KB][KB];
    __shared__ double Mt[KB][KB + 1];
    int b = blockIdx.x, jt = blockIdx.y * 64;
    const T* Bo = Bb + (size_t)b * KB * KB;
    T* Mb = M + ((size_t)b * NN + k0) * NN;
    int t = threadIdx.x;
    for (int e = t; e < KB * KB; e += 256) {
        int rr = e >> 6, cc = e & 63;
        Bi[rr][cc] = (double)Bo[e];
        Mt[rr][cc] = (double)Mb[(size_t)rr * NN + jt + cc];
    }
    __syncthreads();
    if (blockIdx.y == (unsigned)(k0 >> 6)) {
        for (int e = t; e < KB * KB; e += 256) {
            int rr = e >> 6, cc = e & 63;
            Mb[(size_t)rr * NN + jt + cc] = (T)Bi[rr][cc];
        }
        return;
    }
    int tx = t & 15, ty = t >> 4;
    double acc[4][4] = {};
    for (int k = 0; k < KB; ++k) {
        double av[4], bv[4];
#pragma unroll
        for (int u = 0; u < 4; ++u) { av[u] = Bi[ty * 4 + u][k]; bv[u] = Mt[k][tx * 4 + u]; }
#pragma unroll
        for (int u = 0; u < 4; ++u)
#pragma unroll
            for (int v = 0; v < 4; ++v) acc[u][v] += av[u] * bv[v];
    }
#pragma unroll
    for (int u = 0; u < 4; ++u)
#pragma unroll
        for (int v = 0; v < 4; ++v)
            Mb[(size_t)(ty * 4 + u) * NN + jt + tx * 4 + v] = (T)acc[u][v];
}

template <typename T>
__global__ void k_update(T* __restrict__ M, const T* __restrict__ Cb, int k0) {
    int step = k0 >> 6;
    int it = blockIdx.y;
    if (it == step) return;
    int b = blockIdx.x, jt = blockIdx.z;
    __shared__ double Ct[KB][KB + 1];
    __shared__ double Rt[KB][KB + 1];
    int t = threadIdx.x;
    const T* Cbb = Cb + ((size_t)b * NN + it * 64) * KB;
    const T* Rb  = M + ((size_t)b * NN + k0) * NN + jt * 64;
    for (int e = t; e < KB * KB; e += 256) {
        int rr = e >> 6, cc = e & 63;
        Ct[rr][cc] = (double)Cbb[(size_t)rr * KB + cc];
        Rt[rr][cc] = (double)Rb[(size_t)rr * NN + cc];
    }
    __syncthreads();
    int tx = t & 15, ty = t >> 4;
    double acc[4][4] = {};
    for (int k = 0; k < KB; ++k) {
        double av[4], bv[4];
#pragma unroll
        for (int u = 0; u < 4; ++u) { av[u] = Ct[ty * 4 + u][k]; bv[u] = Rt[k][tx * 4 + u]; }
#pragma unroll
        for (int u = 0; u < 4; ++u)
#pragma unroll
            for (int v = 0; v < 4; ++v) acc[u][v] += av[u] * bv[v];
    }
    T* Mo = M + ((size_t)b * NN + it * 64) * NN + jt * 64;
    bool blockcol = (jt == step);
#pragma unroll
    for (int u = 0; u < 4; ++u) {
        int row = ty * 4 + u;
#pragma unroll
        for (int v = 0; v < 4; ++v) {
            int col = tx * 4 + v;
            double val = (double)Mo[(size_t)row * NN + col] - acc[u][v];
            if (blockcol) val -= Ct[row][col];
            Mo[(size_t)row * NN + col] = (T)val;
        }
    }
}

// ---------------- diag extraction + BCE loss ----------------
template <typename T>
__global__ void k_dgloss(const T* __restrict__ M, const float* __restrict__ R,
                         const float* __restrict__ rlab, const int* __restrict__ rmask,
                         double* __restrict__ Dg, float* __restrict__ lossp) {
    int idx = blockIdx.x * 256 + threadIdx.x;
    int b = idx >> 9, n = idx & 511;
    double xv = (double)M[((size_t)b * NN + n) * NN + n];
    Dg[idx] = xv;
    float d0 = R[idx] * (float)xv;
    float lg = fminf(fmaxf(d0, 1e-5f), 1.f - 1e-5f);
    float rm = (float)rmask[idx];
    float lab = (rmask[idx] == 1) ? rlab[idx] : 0.f;
    float bce = -(lab * logf(lg) + (1.f - lab) * logf(1.f - lg));
    __shared__ double sm[256];
    sm[threadIdx.x] = (double)(bce * rm);
    __syncthreads();
    for (int s = 128; s; s >>= 1) {
        if (threadIdx.x < s) sm[threadIdx.x] += sm[threadIdx.x + s];
        __syncthreads();
    }
    if (threadIdx.x == 0) lossp[blockIdx.x] = (float)sm[0];
}

__global__ void k_lossfin(const float* __restrict__ lossp, float* __restrict__ outv) {
    __shared__ double sm[128];
    sm[threadIdx.x] = (double)lossp[threadIdx.x];
    __syncthreads();
    for (int s = 64; s; s >>= 1) {
        if (threadIdx.x < s) sm[threadIdx.x] += sm[threadIdx.x + s];
        __syncthreads();
    }
    if (threadIdx.x == 0) outv[0] = (float)(sm[0] / (double)(BB * NN));
}

// ---------------- d (fallback) ----------------
template <typename T>
__global__ void k_d(const T* __restrict__ M, const double* __restrict__ Dg,
                    const float* __restrict__ adj, const float* __restrict__ mask,
                    float* __restrict__ dout) {
    int b = blockIdx.x, i0 = blockIdx.y * 64, j0 = blockIdx.z * 64;
    __shared__ double Xt[64][65];
    int t = threadIdx.x, ii = t & 63, jj0 = t >> 6;
    const T* Mb = M + (size_t)b * NN * NN;
    for (int jj = jj0; jj < 64; jj += 4)
        Xt[jj][ii] = (double)Mb[(size_t)(j0 + jj) * NN + i0 + ii];
    __syncthreads();
    int jc = t & 63, ir0 = t >> 6;
    float mj = mask[b * NN + j0 + jc] * -1e-4f;
    double dg = Dg[b * NN + j0 + jc];
    const float* ab = adj + (size_t)b * NN * NN;
    float* db = dout + (size_t)b * NN * NN;
    for (int ir = ir0; ir < 64; ir += 4) {
        int i = i0 + ir;
        float mi = mask[b * NN + i] * -1e-4f;
        float a = aval(ab[(size_t)i * NN + j0 + jc], mi, mj);
        db[(size_t)i * NN + j0 + jc] = a * (float)(dg - Xt[jc][ir]);
    }
}

// ---------------- d + transposed masked bf16 hi/lo attn ----------------
template <typename T>
__global__ void k_d2(const T* __restrict__ M, const double* __restrict__ Dg,
                     const float* __restrict__ adj, const float* __restrict__ mask,
                     float* __restrict__ dout,
                     unsigned short* __restrict__ ATh, unsigned short* __restrict__ ATl) {
    int b = blockIdx.x, i0 = blockIdx.y * 64, j0 = blockIdx.z * 64;
    __shared__ double Xt[64][65];
    __shared__ float dt[64][65];
    int t = threadIdx.x, ii = t & 63, jj0 = t >> 6;
    const T* Mb = M + (size_t)b * NN * NN;
    for (int jj = jj0; jj < 64; jj += 4)
        Xt[jj][ii] = (double)Mb[(size_t)(j0 + jj) * NN + i0 + ii];
    __syncthreads();
    int jc = t & 63, ir0 = t >> 6;
    float mj = mask[b * NN + j0 + jc] * -1e-4f;
    double dg = Dg[b * NN + j0 + jc];
    const float* ab = adj + (size_t)b * NN * NN;
    float* db = dout + (size_t)b * NN * NN;
    for (int ir = ir0; ir < 64; ir += 4) {
        int i = i0 + ir;
        float mi = mask[b * NN + i] * -1e-4f;
        float a = aval(ab[(size_t)i * NN + j0 + jc], mi, mj);
        float v = a * (float)(dg - Xt[jc][ir]);
        db[(size_t)i * NN + j0 + jc] = v;
        dt[ir][jc] = v;
    }
    __syncthreads();
    int ql = t >> 2, kq = t & 3;
    us8 vh0, vh1, vl0, vl1;
#pragma unroll
    for (int u = 0; u < 16; ++u) {
        int k = kq * 16 + u;
        float mk = mask[b * NN + i0 + k] * -1e-4f;
        float v = (mk > 0.5f) ? 0.f : dt[k][ql];
        unsigned short h = f2bf(v);
        unsigned short lo = f2bf(v - bf2f(h));
        if (u < 8) { vh0[u] = h; vl0[u] = lo; } else { vh1[u - 8] = h; vl1[u - 8] = lo; }
    }
    size_t ao = ((size_t)b * NN + j0 + ql) * NN + i0 + kq * 16;
    *(us8*)&ATh[ao] = vh0; *(us8*)&ATh[ao + 8] = vh1;
    *(us8*)&ATl[ao] = vl0; *(us8*)&ATl[ao + 8] = vl1;
}

// ---------------- x -> transposed bf16 hi/lo ----------------
__global__ void k_cvt_x(const float* __restrict__ x,
                        unsigned short* __restrict__ XTh, unsigned short* __restrict__ XTl) {
    int b = blockIdx.x, k0 = blockIdx.y * 64, c0 = blockIdx.z * 64;
    __shared__ float xs[64][65];
    int t = threadIdx.x;
#pragma unroll
    for (int rep = 0; rep < 16; ++rep) {
        int e = rep * 256 + t;
        int row = e >> 6, col = e & 63;
        xs[row][col] = x[((size_t)b * NN + k0 + row) * DD + c0 + col];
    }
    __syncthreads();
    int cl = t >> 2, kq = t & 3;
    us8 vh0, vh1, vl0, vl1;
#pragma unroll
    for (int u = 0; u < 16; ++u) {
        int k = kq * 16 + u;
        float v = xs[k][cl];
        unsigned short h = f2bf(v);
        unsigned short lo = f2bf(v - bf2f(h));
        if (u < 8) { vh0[u] = h; vl0[u] = lo; } else { vh1[u - 8] = h; vl1[u - 8] = lo; }
    }
    size_t ao = ((size_t)b * DD + c0 + cl) * NN + k0 + kq * 16;
    *(us8*)&XTh[ao] = vh0; *(us8*)&XTh[ao + 8] = vh1;
    *(us8*)&XTl[ao] = vl0; *(us8*)&XTl[ao + 8] = vl1;
}

// ---------------- context GEMM: MFMA bf16 ----------------
__global__ __launch_bounds__(256) void k_ctx2(const unsigned short* __restrict__ ATh,
                                              const unsigned short* __restrict__ ATl,
                                              const unsigned short* __restrict__ XTh,
                                              const unsigned short* __restrict__ XTl,
                                              float* __restrict__ ctx) {
    __shared__ __align__(16) unsigned short As[128 * 64];
    __shared__ __align__(16) unsigned short Bs[128 * 64];
    int b = blockIdx.x;
    int bm = blockIdx.y * 128, bn = blockIdx.z * 128;
    int t = threadIdx.x, wid = t >> 6, lane = t & 63;
    f32x4 acc[4][4];
#pragma unroll
    for (int i = 0; i < 4; ++i)
#pragma unroll
        for (int j = 0; j < 4; ++j) acc[i][j] = (f32x4){0.f, 0.f, 0.f, 0.f};

    const unsigned short* Asrc[3] = {ATh, ATh, ATl};
    const unsigned short* Bsrc[3] = {XTh, XTl, XTh};

    for (int kt = 0; kt < 24; ++kt) {
        int p = kt >> 3, ki = (kt & 7) * 64;
        const unsigned short* Ag = Asrc[p] + ((size_t)b * NN + bm) * NN + ki;
        const unsigned short* Bg = Bsrc[p] + ((size_t)b * DD + bn) * NN + ki;
        __syncthreads();
#pragma unroll
        for (int it = 0; it < 4; ++it) {
            int chunk = it * 256 + wid * 64 + lane;
            int row = chunk >> 3;
            int lc = (chunk & 7) ^ (row & 7);
            gl_lds16(Ag + (size_t)row * NN + lc * 8, &As[(it * 256 + wid * 64) * 8]);
        }
#pragma unroll
        for (int it = 0; it < 4; ++it) {
            int chunk = it * 256 + wid * 64 + lane;
            int row = chunk >> 3;
            int lc = (chunk & 7) ^ (row & 7);
            gl_lds16(Bg + (size_t)row * NN + lc * 8, &Bs[(it * 256 + wid * 64) * 8]);
        }
        __syncthreads();
        int m0 = (wid >> 1) * 64, n0 = (wid & 1) * 64;
#pragma unroll
        for (int kk = 0; kk < 2; ++kk) {
            bf16x8 af[4], bfr[4];
            int kc = kk * 4 + (lane >> 4);
#pragma unroll
            for (int f = 0; f < 4; ++f) {
                int arow = m0 + f * 16 + (lane & 15);
                af[f] = *(const bf16x8*)&As[arow * 64 + ((kc ^ (arow & 7)) * 8)];
                int brow = n0 + f * 16 + (lane & 15);
                bfr[f] = *(const bf16x8*)&Bs[brow * 64 + ((kc ^ (brow & 7)) * 8)];
            }
#pragma unroll
            for (int fm = 0; fm < 4; ++fm)
#pragma unroll
                for (int fn = 0; fn < 4; ++fn)
                    acc[fm][fn] = __builtin_amdgcn_mfma_f32_16x16x32_bf16(af[fm], bfr[fn], acc[fm][fn], 0, 0, 0);
        }
    }
    int m0 = (wid >> 1) * 64, n0 = (wid & 1) * 64;
    float* cb = ctx + ((size_t)b * NN + bm + m0) * DD + bn + n0;
#pragma unroll
    for (int fm = 0; fm < 4; ++fm)
#pragma unroll
        for (int fn = 0; fn < 4; ++fn)
#pragma unroll
            for (int r = 0; r < 4; ++r) {
                int row = fm * 16 + (lane >> 4) * 4 + r;
                int col = fn * 16 + (lane & 15);
                cb[(size_t)row * DD + col] = acc[fm][fn][r];
            }
}

// ---------------- context (fallback) ----------------
__global__ void k_ctx(const float* __restrict__ dmat, const float* __restrict__ x,
                      const float* __restrict__ mask, float* __restrict__ ctx) {
    int b = blockIdx.x, i0 = blockIdx.y * 64, c0 = blockIdx.z * 64;
    __shared__ float At[32][65];
    __shared__ float Xl[32][65];
    int t = threadIdx.x;
    int tx = t & 15, ty = t >> 4;
    float acc[4][4] = {};
    const float* db = dmat + (size_t)b * NN * NN;
    const float* xb = x + (size_t)b * NN * DD;
    int li = t & 63, lk = t >> 6;
    for (int kt = 0; kt < NN; kt += 32) {
#pragma unroll
        for (int rep = 0; rep < 8; ++rep) {
            int kk = lk + rep * 4;
            float mk = mask[b * NN + kt + kk] * -1e-4f;
            float v = db[(size_t)(kt + kk) * NN + i0 + li];
            At[kk][li] = (mk > 0.5f) ? 0.f : v;
            Xl[kk][li] = xb[(size_t)(kt + kk) * DD + c0 + li];
        }
        __syncthreads();
        for (int kk = 0; kk < 32; ++kk) {
            float av[4], bv[4];
#pragma unroll
            for (int u = 0; u < 4; ++u) { av[u] = At[kk][ty * 4 + u]; bv[u] = Xl[kk][tx * 4 + u]; }
#pragma unroll
            for (int u = 0; u < 4; ++u)
#pragma unroll
                for (int v = 0; v < 4; ++v) acc[u][v] += av[u] * bv[v];
        }
        __syncthreads();
    }
    float* cb = ctx + (size_t)b * NN * DD;
#pragma unroll
    for (int u = 0; u < 4; ++u)
#pragma unroll
        for (int v = 0; v < 4; ++v)
            cb[(size_t)(i0 + ty * 4 + u) * DD + c0 + tx * 4 + v] = acc[u][v];
}

// ================= DEBUG SHADOW: probes / verifies / signals =================
__global__ void k_zerocls(int* cls) { if (threadIdx.x < 8) cls[threadIdx.x] = 0; }

// Raw single-MFMA layout probe with asymmetric A,B.
__global__ void k_probe(int* cls) {
    __shared__ double Am[16][4], Bm[4][16], Dm[16][16], er[16][3];
    int l = threadIdx.x;   // 64
    if (l < 16) for (int k = 0; k < 4; ++k) Am[l][k] = 1.0 + l * 0.5 + k * 7.25;
    if (l < 4)  for (int j = 0; j < 16; ++j) Bm[l][j] = 2.0 + l * 1.5 - j * 0.25;
    __syncthreads();
    double a = Am[l & 15][l >> 4];
    double b = Bm[l >> 4][l & 15];
    f64x4 acc = {0., 0., 0., 0.};
    acc = __builtin_amdgcn_mfma_f64_16x16x4f64(a, b, acc, 0, 0, 0);
#pragma unroll
    for (int r = 0; r < 4; ++r) Dm[(l >> 4) * 4 + r][l & 15] = acc[r];
    __syncthreads();
    if (l < 16) {
        double e0 = 0, e1 = 0, e2 = 0;
        for (int j = 0; j < 16; ++j) {
            double E = 0, Es = 0, ET = 0;
            for (int k = 0; k < 4; ++k) {
                E  += Am[l][k] * Bm[k][j];
                Es += Am[(l >> 2) + 4 * (l & 3)][k] * Bm[k][j];
                ET += Am[j][k] * Bm[k][l];
            }
            e0 = fmax(e0, fabs(Dm[l][j] - E));
            e1 = fmax(e1, fabs(Dm[l][j] - Es));
            e2 = fmax(e2, fabs(Dm[l][j] - ET));
        }
        er[l][0] = e0; er[l][1] = e1; er[l][2] = e2;
    }
    __syncthreads();
    if (l == 0) {
        double m0 = 0, m1 = 0, m2 = 0;
        for (int i = 0; i < 16; ++i) {
            m0 = fmax(m0, er[i][0]); m1 = fmax(m1, er[i][1]); m2 = fmax(m2, er[i][2]);
        }
        cls[0] = (m0 < 1e-9) ? 0 : (m1 < 1e-9) ? 1 : (m2 < 1e-9) ? 2 : 3;
    }
}

__device__ __forceinline__ double blockmax(double v) {
    __shared__ double red[256];
    int t = threadIdx.x;
    red[t] = v; __syncthreads();
    for (int s = 128; s; s >>= 1) { if (t < s) red[t] = fmax(red[t], red[t + s]); __syncthreads(); }
    double r = red[0]; __syncthreads();
    return r;
}

// verify piv_mfma step0 tile (rows 0..63, cols 64..127), b in {0,63}
__global__ void k_verify_piv(const double* __restrict__ Ms, const double* __restrict__ Bb,
                             const float* __restrict__ adj, const float* __restrict__ mask,
                             int* cls) {
    int b = blockIdx.x ? (BB - 1) : 0;
    __shared__ double Bi[64][65];
    __shared__ float Ac[64][65];
    int t = threadIdx.x;
    const double* Bg = Bb + (size_t)b * KB * KB;
    const float* ab = adj + (size_t)b * NN * NN;
    for (int e = t; e < 4096; e += 256) {
        int r = e >> 6, c = e & 63;
        Bi[r][c] = Bg[e];
        float mr = mask[b * NN + r] * -1e-4f;
        float mc = mask[b * NN + 64 + c] * -1e-4f;
        Ac[r][c] = -aval(ab[(size_t)r * NN + 64 + c], mr, mc);
    }
    __syncthreads();
    int i = t >> 2, cq = t & 3;
    double e0 = 0, e1 = 0;
    const double* Mt = Ms + (size_t)b * NN * NN;
    int w16 = i & 48, p = i & 15;
    int sig = w16 + ((p >> 2) + 4 * (p & 3));
    for (int u = 0; u < 16; ++u) {
        int c = cq * 16 + u;
        double E = 0, E2 = 0;
        for (int r = 0; r < 64; ++r) {
            E  += Bi[i][r]   * (double)Ac[r][c];
            E2 += Bi[sig][r] * (double)Ac[r][c];
        }
        double obs = Mt[(size_t)i * NN + 64 + c];
        e0 = fmax(e0, fabs(obs - E)  / (fabs(E)  + 1e-3));
        e1 = fmax(e1, fabs(obs - E2) / (fabs(E2) + 1e-3));
    }
    double m0 = blockmax(e0);
    double m1 = blockmax(e1);
    if (t == 0) atomicMax(&cls[1], (m0 < 1e-6) ? 0 : (m1 < 1e-6) ? 1 : 3);
}

// verify upd_mfma<0> step0 tile (it=1, jt=1): E = Mold(1,1) - Mold(1,0)*Mnew(0,1)
__global__ void k_verify_upd0(const double* __restrict__ Ms, const float* __restrict__ adj,
                              const float* __restrict__ mask, const float* __restrict__ Rf,
                              const double* __restrict__ Lp, int* cls) {
    int b = blockIdx.x ? (BB - 1) : 0;
    __shared__ double N01[64][65];
    __shared__ float A10[64][65];
    int t = threadIdx.x;
    const double* Mt = Ms + (size_t)b * NN * NN;
    const float* ab = adj + (size_t)b * NN * NN;
    for (int e = t; e < 4096; e += 256) {
        int r = e >> 6, c = e & 63;
        N01[r][c] = Mt[(size_t)r * NN + 64 + c];
        float mr = mask[b * NN + 64 + r] * -1e-4f;
        float mc = mask[b * NN + c] * -1e-4f;
        A10[r][c] = -aval(ab[(size_t)(64 + r) * NN + c], mr, mc);
    }
    __syncthreads();
    int i = t >> 2, cq = t & 3;
    double e0 = 0;
    float mri = mask[b * NN + 64 + i] * -1e-4f;
    for (int u = 0; u < 16; ++u) {
        int c = cq * 16 + u;
        float mc = mask[b * NN + 64 + c] * -1e-4f;
        float a = aval(ab[(size_t)(64 + i) * NN + 64 + c], mri, mc);
        double mold;
        if (i == c) {
            const double* lp = Lp + (size_t)b * 4 * NN;
            int gc = 64 + c;
            double L = lp[gc] + lp[NN + gc] + lp[2 * NN + gc] + lp[3 * NN + gc];
            mold = L - (double)a + (double)Rf[b * NN + gc];
        } else {
            mold = -(double)a;
        }
        double E = mold;
        for (int r = 0; r < 64; ++r) E -= (double)A10[i][r] * N01[r][c];
        double obs = Mt[(size_t)(64 + i) * NN + 64 + c];
        e0 = fmax(e0, fabs(obs - E) / (fabs(E) + 1e-3));
    }
    double m0 = blockmax(e0);
    if (t == 0) atomicMax(&cls[2], (m0 < 1e-6) ? 0 : 3);
}

// verify upd_mfma<1> step0 tile (it=1, jt=0): E = -Mold(1,0)*Binv
__global__ void k_verify_upd1(const double* __restrict__ Ms, const double* __restrict__ Bb,
                              const float* __restrict__ adj, const float* __restrict__ mask,
                              int* cls) {
    int b = blockIdx.x ? (BB - 1) : 0;
    __shared__ double Bi[64][65];
    __shared__ float A10[64][65];
    int t = threadIdx.x;
    const double* Bg = Bb + (size_t)b * KB * KB;
    const double* Mt = Ms + (size_t)b * NN * NN;
    const float* ab = adj + (size_t)b * NN * NN;
    for (int e = t; e < 4096; e += 256) {
        int r = e >> 6, c = e & 63;
        Bi[r][c] = Bg[e];
        float mr = mask[b * NN + 64 + r] * -1e-4f;
        float mc = mask[b * NN + c] * -1e-4f;
        A10[r][c] = -aval(ab[(size_t)(64 + r) * NN + c], mr, mc);
    }
    __syncthreads();
    int i = t >> 2, cq = t & 3;
    double e0 = 0;
    for (int u = 0; u < 16; ++u) {
        int c = cq * 16 + u;
        double E = 0;
        for (int r = 0; r < 64; ++r) E -= (double)A10[i][r] * Bi[r][c];
        double obs = Mt[(size_t)(64 + i) * NN + c];
        e0 = fmax(e0, fabs(obs - E) / (fabs(E) + 1e-3));
    }
    double m0 = blockmax(e0);
    if (t == 0) atomicMax(&cls[3], (m0 < 1e-6) ? 0 : 3);
}

// full X comparison scalar vs MFMA
__global__ void k_cmpX(const double* __restrict__ A, const double* __restrict__ B, int* cls) {
    size_t n = (size_t)BB * NN * NN;
    double e = 0;
    for (size_t i = (size_t)blockIdx.x * 256 + threadIdx.x; i < n; i += (size_t)gridDim.x * 256) {
        double a = A[i], bb = B[i];
        e = fmax(e, fabs(a - bb) / fmax(fabs(a), 1.0));
    }
    double m = blockmax(e);
    if (threadIdx.x == 0)
        atomicMax(&cls[4], (m < 1e-6) ? 0 : (m < 1.0) ? 1 : (m < 1e9) ? 2 : 3);
}

__device__ __forceinline__ void sigspin(int c) {
    long long tgt = 600000LL * (long long)(1 + c);
    long long t0 = clock64();
    while (clock64() - t0 < tgt) {}
}
__global__ void k_sig0_probe(const int* cls) { sigspin(cls[0]); }
__global__ void k_sig1_piv(const int* cls)   { sigspin(cls[1]); }
__global__ void k_sig2_upd0(const int* cls)  { sigspin(cls[2]); }
__global__ void k_sig3_upd1(const int* cls)  { sigspin(cls[3]); }
__global__ void k_sig4_cmp(const int* cls)   { sigspin(cls[4]); }

// ---------------- drivers ----------------
template <typename T>
static void run_old(const float* x, const float* adj, const float* mask,
                    const float* rlab, const int* rmask, const float* w, const float* br,
                    float* ctx, float* dmat, float* lossout,
                    char* ws, hipStream_t stream) {
    size_t off = 0;
    T* M  = (T*)(ws + off); off += (size_t)BB * NN * NN * sizeof(T);
    T* Cb = (T*)(ws + off); off += (size_t)BB * NN * KB * sizeof(T);
    T* Bb = (T*)(ws + off); off += (size_t)BB * KB * KB * sizeof(T);
    double* Lp = (double*)(ws + off); off += (size_t)BB * 4 * NN * 8;
    float* Rf  = (float*)(ws + off);  off += (size_t)BB * NN * 4;
    double* Dg = (double*)(ws + off); off += (size_t)BB * NN * 8;
    float* lossp = (float*)(ws + off);

    k_root<<<BB * NN / 4, 256, 0, stream>>>(x, mask, w, br, Rf);
    k_colsum<<<dim3(BB, 4), 512, 0, stream>>>(adj, mask, Lp);
    k_build<T><<<BB * NN, 512, 0, stream>>>(adj, mask, Rf, Lp, M);
    for (int s = 0; s < NSTEP; ++s) {
        int k0 = s * KB;
        k_savecol<T><<<BB * NN / 4, 256, 0, stream>>>(M, Cb, k0);
        k_invblk<T><<<BB, 256, 0, stream>>>(M, Bb, k0);
        k_pivrows<T><<<dim3(BB, 8), 256, 0, stream>>>(M, Bb, k0);
        k_update<T><<<dim3(BB, 8, 8), 256, 0, stream>>>(M, Cb, k0);
    }
    k_dgloss<T><<<BB * NN / 256, 256, 0, stream>>>(M, Rf, rlab, rmask, Dg, lossp);
    k_lossfin<<<1, 128, 0, stream>>>(lossp, lossout);
    k_d<T><<<dim3(BB, 8, 8), 256, 0, stream>>>(M, Dg, adj, mask, dmat);
    k_ctx<<<dim3(BB, 8, 12), 256, 0, stream>>>(dmat, x, mask, ctx);
}

static void run_debug(const float* x, const float* adj, const float* mask,
                      const float* rlab, const int* rmask, const float* w, const float* br,
                      float* ctx, float* dmat, float* lossout,
                      char* ws, hipStream_t stream) {
    size_t off = 0;
    double* M  = (double*)(ws + off); off += (size_t)BB * NN * NN * 8;
    double* Cb = (double*)(ws + off); off += (size_t)BB * NN * KB * 8;
    double* Bb = (double*)(ws + off); off += (size_t)BB * KB * KB * 8;
    double* Lp = (double*)(ws + off); off += (size_t)BB * 4 * NN * 8;
    float* Rf  = (float*)(ws + off);  off += (size_t)BB * NN * 4;
    double* Dg = (double*)(ws + off); off += (size_t)BB * NN * 8;
    float* lossp = (float*)(ws + off); off += 4096;
    unsigned short* ATh = (unsigned short*)(ws + off); off += (size_t)BB * NN * NN * 2;
    unsigned short* ATl = (unsigned short*)(ws + off); off += (size_t)BB * NN * NN * 2;
    unsigned short* XTh = (unsigned short*)(ws);
    unsigned short* XTl = (unsigned short*)(ws + (size_t)BB * DD * NN * 2);
    int* clsI = (int*)((char*)lossp + 2048);
    double* Msh = (double*)ATh;   // shadow matrix (134 MB) in ATh+ATl region

    // ---- production scalar path (known good) ----
    k_root<<<BB * NN / 4, 256, 0, stream>>>(x, mask, w, br, Rf);
    k_colsum<<<dim3(BB, 4), 512, 0, stream>>>(adj, mask, Lp);
    k_build<double><<<BB * NN, 512, 0, stream>>>(adj, mask, Rf, Lp, M);
    for (int s = 0; s < NSTEP; ++s) {
        int k0 = s * KB;
        k_savecol<double><<<BB * NN / 4, 256, 0, stream>>>(M, Cb, k0);
        k_invblk<double><<<BB, 256, 0, stream>>>(M, Bb, k0);
        k_pivrows<double><<<dim3(BB, 8), 256, 0, stream>>>(M, Bb, k0);
        k_update<double><<<dim3(BB, 8, 8), 256, 0, stream>>>(M, Cb, k0);
    }
    k_dgloss<double><<<BB * NN / 256, 256, 0, stream>>>(M, Rf, rlab, rmask, Dg, lossp);
    k_lossfin<<<1, 128, 0, stream>>>(lossp, lossout);

    // ---- shadow MFMA pipeline + verification (outputs unaffected) ----
    k_zerocls<<<1, 64, 0, stream>>>(clsI);
    k_probe<<<1, 64, 0, stream>>>(clsI);
    k_build<double><<<BB * NN, 512, 0, stream>>>(adj, mask, Rf, Lp, Msh);
    for (int s = 0; s < NSTEP; ++s) {
        k_invblk<double><<<BB, 256, 0, stream>>>(Msh, Bb, s * KB);
        k_piv_mfma<<<dim3(8, BB), 256, 0, stream>>>(Msh, Bb, s);
        if (s == 0) k_verify_piv<<<2, 256, 0, stream>>>(Msh, Bb, adj, mask, clsI);
        k_upd_mfma<0><<<dim3(49, BB), 256, 0, stream>>>(Msh, s);
        if (s == 0) k_verify_upd0<<<2, 256, 0, stream>>>(Msh, adj, mask, Rf, Lp, clsI);
        k_upd_mfma<1><<<dim3(7, BB), 256, 0, stream>>>(Msh, s);
        if (s == 0) k_verify_upd1<<<2, 256, 0, stream>>>(Msh, Bb, adj, mask, clsI);
    }
    k_cmpX<<<512, 256, 0, stream>>>(M, Msh, clsI);
    k_sig0_probe<<<1, 64, 0, stream>>>(clsI);
    k_sig1_piv<<<1, 64, 0, stream>>>(clsI);
    k_sig2_upd0<<<1, 64, 0, stream>>>(clsI);
    k_sig3_upd1<<<1, 64, 0, stream>>>(clsI);
    k_sig4_cmp<<<1, 64, 0, stream>>>(clsI);

    // ---- epilogue (overwrites shadow regions with real AT/XT data) ----
    k_d2<double><<<dim3(BB, 8, 8), 256, 0, stream>>>(M, Dg, adj, mask, dmat, ATh, ATl);
    k_cvt_x<<<dim3(BB, 8, 12), 256, 0, stream>>>(x, XTh, XTl);
    k_ctx2<<<dim3(BB, 4, 6), 256, 0, stream>>>(ATh, ATl, XTh, XTl, ctx);
}

extern "C" void kernel_launch(void* const* d_in, const int* in_sizes, int n_in,
                              void* d_out, int out_size, void* d_ws, size_t ws_size,
                              hipStream_t stream) {
    const float* x    = (const float*)d_in[0];
    const float* adj  = (const float*)d_in[1];
    const float* mask = (const float*)d_in[2];
    const float* rlab = (const float*)d_in[3];
    const int*   rmask= (const int*)d_in[4];
    const float* w    = (const float*)d_in[5];
    const float* br   = (const float*)d_in[6];
    float* out = (float*)d_out;
    float* ctx = out;
    float* dmat = out + (size_t)BB * NN * DD;
    float* lossout = dmat + (size_t)BB * NN * NN;
    char* ws = (char*)d_ws;

    size_t base = (size_t)BB * NN * NN * 8 + (size_t)BB * NN * KB * 8 + (size_t)BB * KB * KB * 8
                + (size_t)BB * 4 * NN * 8 + (size_t)BB * NN * 4 + (size_t)BB * NN * 8 + 4096;
    size_t need_new = base + (size_t)BB * NN * NN * 4;
    if (ws_size >= need_new)
        run_debug(x, adj, mask, rlab, rmask, w, br, ctx, dmat, lossout, ws, stream);
    else if (ws_size >= base)
        run_old<double>(x, adj, mask, rlab, rmask, w, br, ctx, dmat, lossout, ws, stream);
    else
        run_old<float>(x, adj, mask, rlab, rmask, w, br, ctx, dmat, lossout, ws, stream);
}

// Round 5
// 1709.040 us; speedup vs baseline: 4.5015x; 4.5015x over previous
//
#include <hip/hip_runtime.h>
#include <cstdint>
#include <cstddef>

#define BB 64
#define NN 512
#define DD 768
#define KB 64
#define NSTEP (NN/KB)

typedef __bf16 bf16x8 __attribute__((ext_vector_type(8)));
typedef float f32x4 __attribute__((ext_vector_type(4)));
typedef unsigned short us8 __attribute__((ext_vector_type(8)));
typedef double f64x4 __attribute__((ext_vector_type(4)));
typedef double f64x2 __attribute__((ext_vector_type(2)));

__device__ __forceinline__ float aval(float adjv, float mi, float mj) {
    return expf(fmaxf(adjv - 50.f * (mi + mj), -40.f));
}

__device__ __forceinline__ unsigned short f2bf(float v) {
    union { float f; unsigned int u; } c; c.f = v;
    return (unsigned short)((c.u + 0x7fffu + ((c.u >> 16) & 1u)) >> 16);
}
__device__ __forceinline__ float bf2f(unsigned short h) {
    union { unsigned int u; float f; } c; c.u = ((unsigned int)h) << 16;
    return c.f;
}

__device__ __forceinline__ void gl_lds16(const void* g, void* l) {
    __builtin_amdgcn_global_load_lds((const __attribute__((address_space(1))) unsigned int*)g,
                                     (__attribute__((address_space(3))) unsigned int*)l, 16, 0, 0);
}

// ---------------- root / R ----------------
__global__ void k_root(const float* __restrict__ x, const float* __restrict__ mask,
                       const float* __restrict__ w, const float* __restrict__ br,
                       float* __restrict__ R) {
    int wave = threadIdx.x >> 6, lane = threadIdx.x & 63;
    int row = blockIdx.x * 4 + wave;
    const float* xr = x + (size_t)row * DD;
    float s = 0.f;
#pragma unroll
    for (int k = 0; k < DD / 64; ++k) s += xr[k * 64 + lane] * w[k * 64 + lane];
    for (int off = 32; off; off >>= 1) s += __shfl_down(s, off, 64);
    if (lane == 0) {
        float m = mask[row] * -1e-4f;
        float rv = fmaxf(s + br[0] - 50.f * m, -40.f);
        R[row] = expf(rv);
    }
}

// ---------------- column sums of A (partials) ----------------
__global__ void k_colsum(const float* __restrict__ adj, const float* __restrict__ mask,
                         double* __restrict__ Lp) {
    int b = blockIdx.x, chunk = blockIdx.y;
    int j = threadIdx.x;
    float mj = mask[b * NN + j] * -1e-4f;
    const float* ab = adj + (size_t)b * NN * NN;
    double acc = 0.0;
    int i0 = chunk * 128;
    for (int i = i0; i < i0 + 128; ++i) {
        float mi = mask[b * NN + i] * -1e-4f;
        acc += (double)aval(ab[(size_t)i * NN + j], mi, mj);
    }
    Lp[((size_t)b * 4 + chunk) * NN + j] = acc;
}

// ---------------- build LL (gate: run only if *gate!=0; nullptr = always) ----------------
template <typename T>
__global__ void k_build(const float* __restrict__ adj, const float* __restrict__ mask,
                        const float* __restrict__ R, const double* __restrict__ Lp,
                        T* __restrict__ M, const int* gate) {
    if (gate && gate[0] == 0) return;
    int b = blockIdx.x >> 9;
    int r = blockIdx.x & 511;
    int c = threadIdx.x;
    float mr = mask[b * NN + r] * -1e-4f;
    float mc = mask[b * NN + c] * -1e-4f;
    size_t idx = ((size_t)b * NN + r) * NN + c;
    float a = aval(adj[idx], mr, mc);
    T v;
    if (r == c) {
        const double* lp = Lp + (size_t)b * 4 * NN;
        double L = lp[c] + lp[NN + c] + lp[2 * NN + c] + lp[3 * NN + c];
        v = (T)(L - (double)a + (double)R[b * NN + c]);
    } else {
        v = (T)(-a);
    }
    M[idx] = v;
}

// ---------------- save column panel (fallback) ----------------
template <typename T>
__global__ void k_savecol(const T* __restrict__ M, T* __restrict__ Cb, int k0, const int* gate) {
    if (gate && gate[0] == 0) return;
    int t = threadIdx.x;
    int c = t & 63, rr = t >> 6;
    int row = blockIdx.x * 4 + rr;
    int b = row >> 9, i = row & 511;
    Cb[(size_t)row * KB + c] = M[((size_t)b * NN + i) * NN + k0 + c];
}

// ---------------- invert 64x64 pivot block ----------------
template <typename T>
__global__ void k_invblk(const T* __restrict__ M, T* __restrict__ Bb, int k0, const int* gate) {
    if (gate && gate[0] == 0) return;
    __shared__ double pr[KB];
    __shared__ double fv[KB];
    __shared__ double pvt;
    int b = blockIdx.x;
    int r = threadIdx.x & 63, q = threadIdx.x >> 6;
    double a[16];
    const T* Mb = M + ((size_t)b * NN + k0) * NN + k0;
#pragma unroll
    for (int c = 0; c < 16; ++c) a[c] = (double)Mb[(size_t)r * NN + q * 16 + c];
    for (int k = 0; k < KB; ++k) {
        int kq = k >> 4, kc = k & 15;
        if (r == k && q == kq) pvt = a[kc];
        __syncthreads();
        double ip = 1.0 / pvt;
        if (r == k) {
#pragma unroll
            for (int c = 0; c < 16; ++c) a[c] *= ip;
            if (q == kq) a[kc] = ip;
#pragma unroll
            for (int c = 0; c < 16; ++c) pr[q * 16 + c] = a[c];
        }
        if (r != k && q == kq) fv[r] = a[kc];
        __syncthreads();
        if (r != k) {
            double f = fv[r];
#pragma unroll
            for (int c = 0; c < 16; ++c) a[c] -= f * pr[q * 16 + c];
            if (q == kq) a[kc] = -f * ip;
        }
        __syncthreads();
    }
    T* Bo = Bb + (size_t)b * KB * KB;
#pragma unroll
    for (int c = 0; c < 16; ++c) Bo[r * KB + q * 16 + c] = (T)a[c];
}

// ---------------- MFMA pivot rows: M[step rows, jt] = Binv @ Mold ----------------
// f64 16x16x4 C/D map (sigma-fixed): row = (lane>>4) + 4*reg, col = lane&15
__global__ __launch_bounds__(256) void k_piv_mfma(double* __restrict__ M,
                                                  const double* __restrict__ Bb, int step) {
    __shared__ double Ms[64][66];
    int b = blockIdx.y, jt = blockIdx.x;
    int t = threadIdx.x, w = t >> 6, l = t & 63;
    double* Mb = M + (size_t)b * NN * NN;
    double* Pr = Mb + (size_t)(step * 64) * NN;
    const double* Bi = Bb + (size_t)b * KB * KB;
    if (jt == step) {
        for (int i = 0; i < 16; ++i) {
            int c = i * 256 + t;
            int row = c >> 6, col = c & 63;
            Pr[(size_t)row * NN + step * 64 + col] = Bi[row * 64 + col];
        }
        return;
    }
    const double* Mg = Pr + jt * 64;
    for (int i = 0; i < 8; ++i) {
        int c = i * 256 + t;
        int row = c >> 5, ch = c & 31;
        f64x2 v = *(const f64x2*)(Mg + (size_t)row * NN + ch * 2);
        Ms[row][ch * 2] = v[0]; Ms[row][ch * 2 + 1] = v[1];
    }
    __syncthreads();
    int lr = l & 15, lg = l >> 4;
    double a[16];
#pragma unroll
    for (int kk = 0; kk < 16; ++kk) a[kk] = Bi[(w * 16 + lr) * 64 + kk * 4 + lg];
    double* Og = Pr + (size_t)(w * 16) * NN + jt * 64;
#pragma unroll
    for (int cf = 0; cf < 4; ++cf) {
        f64x4 acc = {0., 0., 0., 0.};
#pragma unroll
        for (int kk = 0; kk < 16; ++kk)
            acc = __builtin_amdgcn_mfma_f64_16x16x4f64(a[kk], Ms[kk * 4 + lg][cf * 16 + lr], acc, 0, 0, 0);
#pragma unroll
        for (int r = 0; r < 4; ++r) Og[(size_t)(lg + 4 * r) * NN + cf * 16 + lr] = acc[r];
    }
}

// ---------------- MFMA rank-64 update ----------------
template <int COLMODE>
__global__ __launch_bounds__(256) void k_upd_mfma(double* __restrict__ M, int step) {
    __shared__ double Cs[64][66];
    int b = blockIdx.y;
    int x = blockIdx.x;
    int it, jt;
    if (COLMODE) { it = x; jt = step; }
    else { it = x / 7; jt = x % 7; if (jt >= step) ++jt; }
    if (it >= step) ++it;
    int t = threadIdx.x, w = t >> 6, l = t & 63;
    double* Mb = M + (size_t)b * NN * NN;
    {
        const double* Cg = Mb + (size_t)(it * 64) * NN + step * 64;
        for (int i = 0; i < 8; ++i) {
            int c = i * 256 + t;
            int row = c >> 5, ch = c & 31;
            f64x2 v = *(const f64x2*)(Cg + (size_t)row * NN + ch * 2);
            Cs[row][ch * 2] = -v[0]; Cs[row][ch * 2 + 1] = -v[1];
        }
    }
    __syncthreads();
    int lr = l & 15, lg = l >> 4;
    double a[16];
#pragma unroll
    for (int kk = 0; kk < 16; ++kk) a[kk] = Cs[w * 16 + lr][kk * 4 + lg];
    const double* Rg = Mb + (size_t)(step * 64) * NN + jt * 64;
    double* Og = Mb + (size_t)(it * 64 + w * 16) * NN + jt * 64;
#pragma unroll
    for (int cf = 0; cf < 4; ++cf) {
        int c0 = cf * 16 + lr;
        f64x4 acc;
        if (COLMODE) {
            acc = (f64x4){0., 0., 0., 0.};
        } else {
#pragma unroll
            for (int r = 0; r < 4; ++r) acc[r] = Og[(size_t)(lg + 4 * r) * NN + c0];
        }
        const double* bp = Rg + (size_t)lg * NN + c0;
#pragma unroll
        for (int kk = 0; kk < 16; ++kk) {
            double bv = bp[(size_t)(kk * 4) * NN];
            acc = __builtin_amdgcn_mfma_f64_16x16x4f64(a[kk], bv, acc, 0, 0, 0);
        }
#pragma unroll
        for (int r = 0; r < 4; ++r) Og[(size_t)(lg + 4 * r) * NN + c0] = acc[r];
    }
}

// ---------------- scalar pivrows / update (gated fallback) ----------------
template <typename T>
__global__ void k_pivrows(T* __restrict__ M, const T* __restrict__ Bb, int k0, const int* gate) {
    if (gate && gate[0] == 0) return;
    __shared__ double Bi[KB][KB];
    __shared__ double Mt[KB][KB + 1];
    int b = blockIdx.x, jt = blockIdx.y * 64;
    const T* Bo = Bb + (size_t)b * KB * KB;
    T* Mb = M + ((size_t)b * NN + k0) * NN;
    int t = threadIdx.x;
    for (int e = t; e < KB * KB; e += 256) {
        int rr = e >> 6, cc = e & 63;
        Bi[rr][cc] = (double)Bo[e];
        Mt[rr][cc] = (double)Mb[(size_t)rr * NN + jt + cc];
    }
    __syncthreads();
    if (blockIdx.y == (unsigned)(k0 >> 6)) {
        for (int e = t; e < KB * KB; e += 256) {
            int rr = e >> 6, cc = e & 63;
            Mb[(size_t)rr * NN + jt + cc] = (T)Bi[rr][cc];
        }
        return;
    }
    int tx = t & 15, ty = t >> 4;
    double acc[4][4] = {};
    for (int k = 0; k < KB; ++k) {
        double av[4], bv[4];
#pragma unroll
        for (int u = 0; u < 4; ++u) { av[u] = Bi[ty * 4 + u][k]; bv[u] = Mt[k][tx * 4 + u]; }
#pragma unroll
        for (int u = 0; u < 4; ++u)
#pragma unroll
            for (int v = 0; v < 4; ++v) acc[u][v] += av[u] * bv[v];
    }
#pragma unroll
    for (int u = 0; u < 4; ++u)
#pragma unroll
        for (int v = 0; v < 4; ++v)
            Mb[(size_t)(ty * 4 + u) * NN + jt + tx * 4 + v] = (T)acc[u][v];
}

template <typename T>
__global__ void k_update(T* __restrict__ M, const T* __restrict__ Cb, int k0, const int* gate) {
    if (gate && gate[0] == 0) return;
    int step = k0 >> 6;
    int it = blockIdx.y;
    if (it == step) return;
    int b = blockIdx.x, jt = blockIdx.z;
    __shared__ double Ct[KB][KB + 1];
    __shared__ double Rt[KB][KB + 1];
    int t = threadIdx.x;
    const T* Cbb = Cb + ((size_t)b * NN + it * 64) * KB;
    const T* Rb  = M + ((size_t)b * NN + k0) * NN + jt * 64;
    for (int e = t; e < KB * KB; e += 256) {
        int rr = e >> 6, cc = e & 63;
        Ct[rr][cc] = (double)Cbb[(size_t)rr * KB + cc];
        Rt[rr][cc] = (double)Rb[(size_t)rr * NN + cc];
    }
    __syncthreads();
    int tx = t & 15, ty = t >> 4;
    double acc[4][4] = {};
    for (int k = 0; k < KB; ++k) {
        double av[4], bv[4];
#pragma unroll
        for (int u = 0; u < 4; ++u) { av[u] = Ct[ty * 4 + u][k]; bv[u] = Rt[k][tx * 4 + u]; }
#pragma unroll
        for (int u = 0; u < 4; ++u)
#pragma unroll
            for (int v = 0; v < 4; ++v) acc[u][v] += av[u] * bv[v];
    }
    T* Mo = M + ((size_t)b * NN + it * 64) * NN + jt * 64;
    bool blockcol = (jt == step);
#pragma unroll
    for (int u = 0; u < 4; ++u) {
        int row = ty * 4 + u;
#pragma unroll
        for (int v = 0; v < 4; ++v) {
            int col = tx * 4 + v;
            double val = (double)Mo[(size_t)row * NN + col] - acc[u][v];
            if (blockcol) val -= Ct[row][col];
            Mo[(size_t)row * NN + col] = (T)val;
        }
    }
}

// ---------------- diag extraction + BCE loss ----------------
template <typename T>
__global__ void k_dgloss(const T* __restrict__ M, const float* __restrict__ R,
                         const float* __restrict__ rlab, const int* __restrict__ rmask,
                         double* __restrict__ Dg, float* __restrict__ lossp) {
    int idx = blockIdx.x * 256 + threadIdx.x;
    int b = idx >> 9, n = idx & 511;
    double xv = (double)M[((size_t)b * NN + n) * NN + n];
    Dg[idx] = xv;
    float d0 = R[idx] * (float)xv;
    float lg = fminf(fmaxf(d0, 1e-5f), 1.f - 1e-5f);
    float rm = (float)rmask[idx];
    float lab = (rmask[idx] == 1) ? rlab[idx] : 0.f;
    float bce = -(lab * logf(lg) + (1.f - lab) * logf(1.f - lg));
    __shared__ double sm[256];
    sm[threadIdx.x] = (double)(bce * rm);
    __syncthreads();
    for (int s = 128; s; s >>= 1) {
        if (threadIdx.x < s) sm[threadIdx.x] += sm[threadIdx.x + s];
        __syncthreads();
    }
    if (threadIdx.x == 0) lossp[blockIdx.x] = (float)sm[0];
}

__global__ void k_lossfin(const float* __restrict__ lossp, float* __restrict__ outv) {
    __shared__ double sm[128];
    sm[threadIdx.x] = (double)lossp[threadIdx.x];
    __syncthreads();
    for (int s = 64; s; s >>= 1) {
        if (threadIdx.x < s) sm[threadIdx.x] += sm[threadIdx.x + s];
        __syncthreads();
    }
    if (threadIdx.x == 0) outv[0] = (float)(sm[0] / (double)(BB * NN));
}

// ---------------- d (fallback path) ----------------
template <typename T>
__global__ void k_d(const T* __restrict__ M, const double* __restrict__ Dg,
                    const float* __restrict__ adj, const float* __restrict__ mask,
                    float* __restrict__ dout) {
    int b = blockIdx.x, i0 = blockIdx.y * 64, j0 = blockIdx.z * 64;
    __shared__ double Xt[64][65];
    int t = threadIdx.x, ii = t & 63, jj0 = t >> 6;
    const T* Mb = M + (size_t)b * NN * NN;
    for (int jj = jj0; jj < 64; jj += 4)
        Xt[jj][ii] = (double)Mb[(size_t)(j0 + jj) * NN + i0 + ii];
    __syncthreads();
    int jc = t & 63, ir0 = t >> 6;
    float mj = mask[b * NN + j0 + jc] * -1e-4f;
    double dg = Dg[b * NN + j0 + jc];
    const float* ab = adj + (size_t)b * NN * NN;
    float* db = dout + (size_t)b * NN * NN;
    for (int ir = ir0; ir < 64; ir += 4) {
        int i = i0 + ir;
        float mi = mask[b * NN + i] * -1e-4f;
        float a = aval(ab[(size_t)i * NN + j0 + jc], mi, mj);
        db[(size_t)i * NN + j0 + jc] = a * (float)(dg - Xt[jc][ir]);
    }
}

// ---------------- d + transposed masked bf16 hi/lo attn ----------------
template <typename T>
__global__ void k_d2(const T* __restrict__ M, const double* __restrict__ Dg,
                     const float* __restrict__ adj, const float* __restrict__ mask,
                     float* __restrict__ dout,
                     unsigned short* __restrict__ ATh, unsigned short* __restrict__ ATl) {
    int b = blockIdx.x, i0 = blockIdx.y * 64, j0 = blockIdx.z * 64;
    __shared__ double Xt[64][65];
    __shared__ float dt[64][65];
    int t = threadIdx.x, ii = t & 63, jj0 = t >> 6;
    const T* Mb = M + (size_t)b * NN * NN;
    for (int jj = jj0; jj < 64; jj += 4)
        Xt[jj][ii] = (double)Mb[(size_t)(j0 + jj) * NN + i0 + ii];
    __syncthreads();
    int jc = t & 63, ir0 = t >> 6;
    float mj = mask[b * NN + j0 + jc] * -1e-4f;
    double dg = Dg[b * NN + j0 + jc];
    const float* ab = adj + (size_t)b * NN * NN;
    float* db = dout + (size_t)b * NN * NN;
    for (int ir = ir0; ir < 64; ir += 4) {
        int i = i0 + ir;
        float mi = mask[b * NN + i] * -1e-4f;
        float a = aval(ab[(size_t)i * NN + j0 + jc], mi, mj);
        float v = a * (float)(dg - Xt[jc][ir]);
        db[(size_t)i * NN + j0 + jc] = v;
        dt[ir][jc] = v;
    }
    __syncthreads();
    int ql = t >> 2, kq = t & 3;
    us8 vh0, vh1, vl0, vl1;
#pragma unroll
    for (int u = 0; u < 16; ++u) {
        int k = kq * 16 + u;
        float mk = mask[b * NN + i0 + k] * -1e-4f;
        float v = (mk > 0.5f) ? 0.f : dt[k][ql];
        unsigned short h = f2bf(v);
        unsigned short lo = f2bf(v - bf2f(h));
        if (u < 8) { vh0[u] = h; vl0[u] = lo; } else { vh1[u - 8] = h; vl1[u - 8] = lo; }
    }
    size_t ao = ((size_t)b * NN + j0 + ql) * NN + i0 + kq * 16;
    *(us8*)&ATh[ao] = vh0; *(us8*)&ATh[ao + 8] = vh1;
    *(us8*)&ATl[ao] = vl0; *(us8*)&ATl[ao + 8] = vl1;
}

// ---------------- x -> transposed bf16 hi/lo ----------------
__global__ void k_cvt_x(const float* __restrict__ x,
                        unsigned short* __restrict__ XTh, unsigned short* __restrict__ XTl) {
    int b = blockIdx.x, k0 = blockIdx.y * 64, c0 = blockIdx.z * 64;
    __shared__ float xs[64][65];
    int t = threadIdx.x;
#pragma unroll
    for (int rep = 0; rep < 16; ++rep) {
        int e = rep * 256 + t;
        int row = e >> 6, col = e & 63;
        xs[row][col] = x[((size_t)b * NN + k0 + row) * DD + c0 + col];
    }
    __syncthreads();
    int cl = t >> 2, kq = t & 3;
    us8 vh0, vh1, vl0, vl1;
#pragma unroll
    for (int u = 0; u < 16; ++u) {
        int k = kq * 16 + u;
        float v = xs[k][cl];
        unsigned short h = f2bf(v);
        unsigned short lo = f2bf(v - bf2f(h));
        if (u < 8) { vh0[u] = h; vl0[u] = lo; } else { vh1[u - 8] = h; vl1[u - 8] = lo; }
    }
    size_t ao = ((size_t)b * DD + c0 + cl) * NN + k0 + kq * 16;
    *(us8*)&XTh[ao] = vh0; *(us8*)&XTh[ao + 8] = vh1;
    *(us8*)&XTl[ao] = vl0; *(us8*)&XTl[ao + 8] = vl1;
}

// ---------------- context GEMM: MFMA bf16 ----------------
__global__ __launch_bounds__(256) void k_ctx2(const unsigned short* __restrict__ ATh,
                                              const unsigned short* __restrict__ ATl,
                                              const unsigned short* __restrict__ XTh,
                                              const unsigned short* __restrict__ XTl,
                                              float* __restrict__ ctx) {
    __shared__ __align__(16) unsigned short As[128 * 64];
    __shared__ __align__(16) unsigned short Bs[128 * 64];
    int b = blockIdx.x;
    int bm = blockIdx.y * 128, bn = blockIdx.z * 128;
    int t = threadIdx.x, wid = t >> 6, lane = t & 63;
    f32x4 acc[4][4];
#pragma unroll
    for (int i = 0; i < 4; ++i)
#pragma unroll
        for (int j = 0; j < 4; ++j) acc[i][j] = (f32x4){0.f, 0.f, 0.f, 0.f};

    const unsigned short* Asrc[3] = {ATh, ATh, ATl};
    const unsigned short* Bsrc[3] = {XTh, XTl, XTh};

    for (int kt = 0; kt < 24; ++kt) {
        int p = kt >> 3, ki = (kt & 7) * 64;
        const unsigned short* Ag = Asrc[p] + ((size_t)b * NN + bm) * NN + ki;
        const unsigned short* Bg = Bsrc[p] + ((size_t)b * DD + bn) * NN + ki;
        __syncthreads();
#pragma unroll
        for (int it = 0; it < 4; ++it) {
            int chunk = it * 256 + wid * 64 + lane;
            int row = chunk >> 3;
            int lc = (chunk & 7) ^ (row & 7);
            gl_lds16(Ag + (size_t)row * NN + lc * 8, &As[(it * 256 + wid * 64) * 8]);
        }
#pragma unroll
        for (int it = 0; it < 4; ++it) {
            int chunk = it * 256 + wid * 64 + lane;
            int row = chunk >> 3;
            int lc = (chunk & 7) ^ (row & 7);
            gl_lds16(Bg + (size_t)row * NN + lc * 8, &Bs[(it * 256 + wid * 64) * 8]);
        }
        __syncthreads();
        int m0 = (wid >> 1) * 64, n0 = (wid & 1) * 64;
#pragma unroll
        for (int kk = 0; kk < 2; ++kk) {
            bf16x8 af[4], bfr[4];
            int kc = kk * 4 + (lane >> 4);
#pragma unroll
            for (int f = 0; f < 4; ++f) {
                int arow = m0 + f * 16 + (lane & 15);
                af[f] = *(const bf16x8*)&As[arow * 64 + ((kc ^ (arow & 7)) * 8)];
                int brow = n0 + f * 16 + (lane & 15);
                bfr[f] = *(const bf16x8*)&Bs[brow * 64 + ((kc ^ (brow & 7)) * 8)];
            }
#pragma unroll
            for (int fm = 0; fm < 4; ++fm)
#pragma unroll
                for (int fn = 0; fn < 4; ++fn)
                    acc[fm][fn] = __builtin_amdgcn_mfma_f32_16x16x32_bf16(af[fm], bfr[fn], acc[fm][fn], 0, 0, 0);
        }
    }
    int m0 = (wid >> 1) * 64, n0 = (wid & 1) * 64;
    float* cb = ctx + ((size_t)b * NN + bm + m0) * DD + bn + n0;
#pragma unroll
    for (int fm = 0; fm < 4; ++fm)
#pragma unroll
        for (int fn = 0; fn < 4; ++fn)
#pragma unroll
            for (int r = 0; r < 4; ++r) {
                int row = fm * 16 + (lane >> 4) * 4 + r;
                int col = fn * 16 + (lane & 15);
                cb[(size_t)row * DD + col] = acc[fm][fn][r];
            }
}

// ---------------- context (fallback) ----------------
__global__ void k_ctx(const float* __restrict__ dmat, const float* __restrict__ x,
                      const float* __restrict__ mask, float* __restrict__ ctx) {
    int b = blockIdx.x, i0 = blockIdx.y * 64, c0 = blockIdx.z * 64;
    __shared__ float At[32][65];
    __shared__ float Xl[32][65];
    int t = threadIdx.x;
    int tx = t & 15, ty = t >> 4;
    float acc[4][4] = {};
    const float* db = dmat + (size_t)b * NN * NN;
    const float* xb = x + (size_t)b * NN * DD;
    int li = t & 63, lk = t >> 6;
    for (int kt = 0; kt < NN; kt += 32) {
#pragma unroll
        for (int rep = 0; rep < 8; ++rep) {
            int kk = lk + rep * 4;
            float mk = mask[b * NN + kt + kk] * -1e-4f;
            float v = db[(size_t)(kt + kk) * NN + i0 + li];
            At[kk][li] = (mk > 0.5f) ? 0.f : v;
            Xl[kk][li] = xb[(size_t)(kt + kk) * DD + c0 + li];
        }
        __syncthreads();
        for (int kk = 0; kk < 32; ++kk) {
            float av[4], bv[4];
#pragma unroll
            for (int u = 0; u < 4; ++u) { av[u] = At[kk][ty * 4 + u]; bv[u] = Xl[kk][tx * 4 + u]; }
#pragma unroll
            for (int u = 0; u < 4; ++u)
#pragma unroll
                for (int v = 0; v < 4; ++v) acc[u][v] += av[u] * bv[v];
        }
        __syncthreads();
    }
    float* cb = ctx + (size_t)b * NN * DD;
#pragma unroll
    for (int u = 0; u < 4; ++u)
#pragma unroll
        for (int v = 0; v < 4; ++v)
            cb[(size_t)(i0 + ty * 4 + u) * DD + c0 + tx * 4 + v] = acc[u][v];
}

// ================= verification / adjudication =================
__global__ void k_zerocls(int* cls) { if (threadIdx.x < 8) cls[threadIdx.x] = 0; }

// probe: class0 = sigma map (row=lg+4r), class1 = old map, class2 = transpose, 3 = other
__global__ void k_probe(int* cls) {
    __shared__ double Am[16][4], Bm[4][16], Dm[16][16], er[16][3];
    int l = threadIdx.x;
    if (l < 16) for (int k = 0; k < 4; ++k) Am[l][k] = 1.0 + l * 0.5 + k * 7.25;
    if (l < 4)  for (int j = 0; j < 16; ++j) Bm[l][j] = 2.0 + l * 1.5 - j * 0.25;
    __syncthreads();
    double a = Am[l & 15][l >> 4];
    double b = Bm[l >> 4][l & 15];
    f64x4 acc = {0., 0., 0., 0.};
    acc = __builtin_amdgcn_mfma_f64_16x16x4f64(a, b, acc, 0, 0, 0);
#pragma unroll
    for (int r = 0; r < 4; ++r) Dm[(l >> 4) + 4 * r][l & 15] = acc[r];
    __syncthreads();
    if (l < 16) {
        double e0 = 0, e1 = 0, e2 = 0;
        int sig = (l >> 2) + 4 * (l & 3);
        for (int j = 0; j < 16; ++j) {
            double E = 0, Es = 0, ET = 0;
            for (int k = 0; k < 4; ++k) {
                E  += Am[l][k] * Bm[k][j];
                Es += Am[sig][k] * Bm[k][j];
                ET += Am[j][k] * Bm[k][l];
            }
            e0 = fmax(e0, fabs(Dm[l][j] - E));
            e1 = fmax(e1, fabs(Dm[l][j] - Es));
            e2 = fmax(e2, fabs(Dm[l][j] - ET));
        }
        er[l][0] = e0; er[l][1] = e1; er[l][2] = e2;
    }
    __syncthreads();
    if (l == 0) {
        double m0 = 0, m1 = 0, m2 = 0;
        for (int i = 0; i < 16; ++i) {
            m0 = fmax(m0, er[i][0]); m1 = fmax(m1, er[i][1]); m2 = fmax(m2, er[i][2]);
        }
        cls[0] = (m0 < 1e-9) ? 0 : (m1 < 1e-9) ? 1 : (m2 < 1e-9) ? 2 : 3;
    }
}

__device__ __forceinline__ double blockmax(double v) {
    __shared__ double red[256];
    int t = threadIdx.x;
    red[t] = v; __syncthreads();
    for (int s = 128; s; s >>= 1) { if (t < s) red[t] = fmax(red[t], red[t + s]); __syncthreads(); }
    double r = red[0]; __syncthreads();
    return r;
}

__global__ void k_verify_piv(const double* __restrict__ Ms, const double* __restrict__ Bb,
                             const float* __restrict__ adj, const float* __restrict__ mask,
                             int* cls) {
    int b = blockIdx.x ? (BB - 1) : 0;
    __shared__ double Bi[64][65];
    __shared__ float Ac[64][65];
    int t = threadIdx.x;
    const double* Bg = Bb + (size_t)b * KB * KB;
    const float* ab = adj + (size_t)b * NN * NN;
    for (int e = t; e < 4096; e += 256) {
        int r = e >> 6, c = e & 63;
        Bi[r][c] = Bg[e];
        float mr = mask[b * NN + r] * -1e-4f;
        float mc = mask[b * NN + 64 + c] * -1e-4f;
        Ac[r][c] = -aval(ab[(size_t)r * NN + 64 + c], mr, mc);
    }
    __syncthreads();
    int i = t >> 2, cq = t & 3;
    double e0 = 0, e1 = 0;
    const double* Mt = Ms + (size_t)b * NN * NN;
    int w16 = i & 48, p = i & 15;
    int sig = w16 + ((p >> 2) + 4 * (p & 3));
    for (int u = 0; u < 16; ++u) {
        int c = cq * 16 + u;
        double E = 0, E2 = 0;
        for (int r = 0; r < 64; ++r) {
            E  += Bi[i][r]   * (double)Ac[r][c];
            E2 += Bi[sig][r] * (double)Ac[r][c];
        }
        double obs = Mt[(size_t)i * NN + 64 + c];
        e0 = fmax(e0, fabs(obs - E)  / (fabs(E)  + 1e-3));
        e1 = fmax(e1, fabs(obs - E2) / (fabs(E2) + 1e-3));
    }
    double m0 = blockmax(e0);
    double m1 = blockmax(e1);
    if (t == 0) atomicMax(&cls[1], (m0 < 1e-6) ? 0 : (m1 < 1e-6) ? 1 : 3);
}

__global__ void k_verify_upd0(const double* __restrict__ Ms, const float* __restrict__ adj,
                              const float* __restrict__ mask, const float* __restrict__ Rf,
                              const double* __restrict__ Lp, int* cls) {
    int b = blockIdx.x ? (BB - 1) : 0;
    __shared__ double N01[64][65];
    __shared__ float A10[64][65];
    int t = threadIdx.x;
    const double* Mt = Ms + (size_t)b * NN * NN;
    const float* ab = adj + (size_t)b * NN * NN;
    for (int e = t; e < 4096; e += 256) {
        int r = e >> 6, c = e & 63;
        N01[r][c] = Mt[(size_t)r * NN + 64 + c];
        float mr = mask[b * NN + 64 + r] * -1e-4f;
        float mc = mask[b * NN + c] * -1e-4f;
        A10[r][c] = -aval(ab[(size_t)(64 + r) * NN + c], mr, mc);
    }
    __syncthreads();
    int i = t >> 2, cq = t & 3;
    double e0 = 0;
    float mri = mask[b * NN + 64 + i] * -1e-4f;
    for (int u = 0; u < 16; ++u) {
        int c = cq * 16 + u;
        float mc = mask[b * NN + 64 + c] * -1e-4f;
        float a = aval(ab[(size_t)(64 + i) * NN + 64 + c], mri, mc);
        double mold;
        if (i == c) {
            const double* lp = Lp + (size_t)b * 4 * NN;
            int gc = 64 + c;
            double L = lp[gc] + lp[NN + gc] + lp[2 * NN + gc] + lp[3 * NN + gc];
            mold = L - (double)a + (double)Rf[b * NN + gc];
        } else {
            mold = -(double)a;
        }
        double E = mold;
        for (int r = 0; r < 64; ++r) E -= (double)A10[i][r] * N01[r][c];
        double obs = Mt[(size_t)(64 + i) * NN + 64 + c];
        e0 = fmax(e0, fabs(obs - E) / (fabs(E) + 1e-3));
    }
    double m0 = blockmax(e0);
    if (t == 0) atomicMax(&cls[2], (m0 < 1e-6) ? 0 : 3);
}

__global__ void k_verify_upd1(const double* __restrict__ Ms, const double* __restrict__ Bb,
                              const float* __restrict__ adj, const float* __restrict__ mask,
                              int* cls) {
    int b = blockIdx.x ? (BB - 1) : 0;
    __shared__ double Bi[64][65];
    __shared__ float A10[64][65];
    int t = threadIdx.x;
    const double* Bg = Bb + (size_t)b * KB * KB;
    const double* Mt = Ms + (size_t)b * NN * NN;
    const float* ab = adj + (size_t)b * NN * NN;
    for (int e = t; e < 4096; e += 256) {
        int r = e >> 6, c = e & 63;
        Bi[r][c] = Bg[e];
        float mr = mask[b * NN + 64 + r] * -1e-4f;
        float mc = mask[b * NN + c] * -1e-4f;
        A10[r][c] = -aval(ab[(size_t)(64 + r) * NN + c], mr, mc);
    }
    __syncthreads();
    int i = t >> 2, cq = t & 3;
    double e0 = 0;
    for (int u = 0; u < 16; ++u) {
        int c = cq * 16 + u;
        double E = 0;
        for (int r = 0; r < 64; ++r) E -= (double)A10[i][r] * Bi[r][c];
        double obs = Mt[(size_t)(64 + i) * NN + c];
        e0 = fmax(e0, fabs(obs - E) / (fabs(E) + 1e-3));
    }
    double m0 = blockmax(e0);
    if (t == 0) atomicMax(&cls[3], (m0 < 1e-6) ? 0 : 3);
}

// end-to-end invariant: root marginals R*diag(X) must lie in [0,1] (matrix-tree)
__global__ void k_sanity(const double* __restrict__ M, const float* __restrict__ Rf, int* cls) {
    int idx = blockIdx.x * 256 + threadIdx.x;
    int b = idx >> 9, n = idx & 511;
    double v = (double)Rf[idx] * M[((size_t)b * NN + n) * NN + n];
    bool ok = (v > -0.01) && (v < 1.01);
    if (!ok) atomicMax(&cls[5], 3);
}

__global__ void k_adj(int* cls) {
    if (threadIdx.x == 0) cls[6] = (cls[1] | cls[2] | cls[3] | cls[5]) ? 1 : 0;
}

// signal: spin only on failure; duration ~ class*(250+25*I) us at 2.4GHz
template <int I>
__global__ void k_sig(const int* cls, int cidx) {
    int c = cls[cidx];
    if (c <= 0) return;
    long long tgt = (long long)c * (600000LL + I * 60000LL);
    long long t0 = clock64();
    while (clock64() - t0 < tgt) {}
}

// ---------------- drivers ----------------
template <typename T>
static void run_old(const float* x, const float* adj, const float* mask,
                    const float* rlab, const int* rmask, const float* w, const float* br,
                    float* ctx, float* dmat, float* lossout,
                    char* ws, hipStream_t stream) {
    size_t off = 0;
    T* M  = (T*)(ws + off); off += (size_t)BB * NN * NN * sizeof(T);
    T* Cb = (T*)(ws + off); off += (size_t)BB * NN * KB * sizeof(T);
    T* Bb = (T*)(ws + off); off += (size_t)BB * KB * KB * sizeof(T);
    double* Lp = (double*)(ws + off); off += (size_t)BB * 4 * NN * 8;
    float* Rf  = (float*)(ws + off);  off += (size_t)BB * NN * 4;
    double* Dg = (double*)(ws + off); off += (size_t)BB * NN * 8;
    float* lossp = (float*)(ws + off);

    k_root<<<BB * NN / 4, 256, 0, stream>>>(x, mask, w, br, Rf);
    k_colsum<<<dim3(BB, 4), 512, 0, stream>>>(adj, mask, Lp);
    k_build<T><<<BB * NN, 512, 0, stream>>>(adj, mask, Rf, Lp, M, nullptr);
    for (int s = 0; s < NSTEP; ++s) {
        int k0 = s * KB;
        k_savecol<T><<<BB * NN / 4, 256, 0, stream>>>(M, Cb, k0, nullptr);
        k_invblk<T><<<BB, 256, 0, stream>>>(M, Bb, k0, nullptr);
        k_pivrows<T><<<dim3(BB, 8), 256, 0, stream>>>(M, Bb, k0, nullptr);
        k_update<T><<<dim3(BB, 8, 8), 256, 0, stream>>>(M, Cb, k0, nullptr);
    }
    k_dgloss<T><<<BB * NN / 256, 256, 0, stream>>>(M, Rf, rlab, rmask, Dg, lossp);
    k_lossfin<<<1, 128, 0, stream>>>(lossp, lossout);
    k_d<T><<<dim3(BB, 8, 8), 256, 0, stream>>>(M, Dg, adj, mask, dmat);
    k_ctx<<<dim3(BB, 8, 12), 256, 0, stream>>>(dmat, x, mask, ctx);
}

static void run_new(const float* x, const float* adj, const float* mask,
                    const float* rlab, const int* rmask, const float* w, const float* br,
                    float* ctx, float* dmat, float* lossout,
                    char* ws, hipStream_t stream) {
    size_t off = 0;
    double* M  = (double*)(ws + off); off += (size_t)BB * NN * NN * 8;
    double* Cb = (double*)(ws + off); off += (size_t)BB * NN * KB * 8;
    double* Bb = (double*)(ws + off); off += (size_t)BB * KB * KB * 8;
    double* Lp = (double*)(ws + off); off += (size_t)BB * 4 * NN * 8;
    float* Rf  = (float*)(ws + off);  off += (size_t)BB * NN * 4;
    double* Dg = (double*)(ws + off); off += (size_t)BB * NN * 8;
    float* lossp = (float*)(ws + off); off += 4096;
    unsigned short* ATh = (unsigned short*)(ws + off); off += (size_t)BB * NN * NN * 2;
    unsigned short* ATl = (unsigned short*)(ws + off); off += (size_t)BB * NN * NN * 2;
    unsigned short* XTh = (unsigned short*)(ws);
    unsigned short* XTl = (unsigned short*)(ws + (size_t)BB * DD * NN * 2);
    int* clsI = (int*)((char*)lossp + 2048);
    int* gate = clsI + 6;

    k_root<<<BB * NN / 4, 256, 0, stream>>>(x, mask, w, br, Rf);
    k_colsum<<<dim3(BB, 4), 512, 0, stream>>>(adj, mask, Lp);
    k_build<double><<<BB * NN, 512, 0, stream>>>(adj, mask, Rf, Lp, M, nullptr);
    k_zerocls<<<1, 64, 0, stream>>>(clsI);
    k_probe<<<1, 64, 0, stream>>>(clsI);
    for (int s = 0; s < NSTEP; ++s) {
        k_invblk<double><<<BB, 256, 0, stream>>>(M, Bb, s * KB, nullptr);
        k_piv_mfma<<<dim3(8, BB), 256, 0, stream>>>(M, Bb, s);
        if (s == 0) k_verify_piv<<<2, 256, 0, stream>>>(M, Bb, adj, mask, clsI);
        k_upd_mfma<0><<<dim3(49, BB), 256, 0, stream>>>(M, s);
        if (s == 0) k_verify_upd0<<<2, 256, 0, stream>>>(M, adj, mask, Rf, Lp, clsI);
        k_upd_mfma<1><<<dim3(7, BB), 256, 0, stream>>>(M, s);
        if (s == 0) k_verify_upd1<<<2, 256, 0, stream>>>(M, Bb, adj, mask, clsI);
    }
    k_sanity<<<BB * NN / 256, 256, 0, stream>>>(M, Rf, clsI);
    k_adj<<<1, 64, 0, stream>>>(clsI);

    // signal kernels (spin only on failure; duration encodes class per kernel)
    k_sig<0><<<1, 64, 0, stream>>>(clsI, 0);
    k_sig<1><<<1, 64, 0, stream>>>(clsI, 1);
    k_sig<2><<<1, 64, 0, stream>>>(clsI, 2);
    k_sig<3><<<1, 64, 0, stream>>>(clsI, 3);
    k_sig<4><<<1, 64, 0, stream>>>(clsI, 5);

    // self-healing scalar fallback (early-exits when gate==0)
    k_build<double><<<BB * NN, 512, 0, stream>>>(adj, mask, Rf, Lp, M, gate);
    for (int s = 0; s < NSTEP; ++s) {
        int k0 = s * KB;
        k_savecol<double><<<BB * NN / 4, 256, 0, stream>>>(M, Cb, k0, gate);
        k_invblk<double><<<BB, 256, 0, stream>>>(M, Bb, k0, gate);
        k_pivrows<double><<<dim3(BB, 8), 256, 0, stream>>>(M, Bb, k0, gate);
        k_update<double><<<dim3(BB, 8, 8), 256, 0, stream>>>(M, Cb, k0, gate);
    }

    k_dgloss<double><<<BB * NN / 256, 256, 0, stream>>>(M, Rf, rlab, rmask, Dg, lossp);
    k_lossfin<<<1, 128, 0, stream>>>(lossp, lossout);
    k_d2<double><<<dim3(BB, 8, 8), 256, 0, stream>>>(M, Dg, adj, mask, dmat, ATh, ATl);
    k_cvt_x<<<dim3(BB, 8, 12), 256, 0, stream>>>(x, XTh, XTl);
    k_ctx2<<<dim3(BB, 4, 6), 256, 0, stream>>>(ATh, ATl, XTh, XTl, ctx);
}

extern "C" void kernel_launch(void* const* d_in, const int* in_sizes, int n_in,
                              void* d_out, int out_size, void* d_ws, size_t ws_size,
                              hipStream_t stream) {
    const float* x    = (const float*)d_in[0];
    const float* adj  = (const float*)d_in[1];
    const float* mask = (const float*)d_in[2];
    const float* rlab = (const float*)d_in[3];
    const int*   rmask= (const int*)d_in[4];
    const float* w    = (const float*)d_in[5];
    const float* br   = (const float*)d_in[6];
    float* out = (float*)d_out;
    float* ctx = out;
    float* dmat = out + (size_t)BB * NN * DD;
    float* lossout = dmat + (size_t)BB * NN * NN;
    char* ws = (char*)d_ws;

    size_t base = (size_t)BB * NN * NN * 8 + (size_t)BB * NN * KB * 8 + (size_t)BB * KB * KB * 8
                + (size_t)BB * 4 * NN * 8 + (size_t)BB * NN * 4 + (size_t)BB * NN * 8 + 4096;
    size_t need_new = base + (size_t)BB * NN * NN * 4;
    if (ws_size >= need_new)
        run_new(x, adj, mask, rlab, rmask, w, br, ctx, dmat, lossout, ws, stream);
    else if (ws_size >= base)
        run_old<double>(x, adj, mask, rlab, rmask, w, br, ctx, dmat, lossout, ws, stream);
    else
        run_old<float>(x, adj, mask, rlab, rmask, w, br, ctx, dmat, lossout, ws, stream);
}

// Round 6
// 1396.078 us; speedup vs baseline: 5.5107x; 1.2242x over previous
//
#include <hip/hip_runtime.h>
#include <cstdint>
#include <cstddef>

#define BB 64
#define NN 512
#define DD 768
#define KB 64
#define NSTEP (NN/KB)

typedef __bf16 bf16x8 __attribute__((ext_vector_type(8)));
typedef float f32x4 __attribute__((ext_vector_type(4)));
typedef unsigned short us8 __attribute__((ext_vector_type(8)));
typedef double f64x4 __attribute__((ext_vector_type(4)));
typedef double f64x2 __attribute__((ext_vector_type(2)));

__device__ __forceinline__ float aval(float adjv, float mi, float mj) {
    return expf(fmaxf(adjv - 50.f * (mi + mj), -40.f));
}

__device__ __forceinline__ unsigned short f2bf(float v) {
    union { float f; unsigned int u; } c; c.f = v;
    return (unsigned short)((c.u + 0x7fffu + ((c.u >> 16) & 1u)) >> 16);
}
__device__ __forceinline__ float bf2f(unsigned short h) {
    union { unsigned int u; float f; } c; c.u = ((unsigned int)h) << 16;
    return c.f;
}

__device__ __forceinline__ void gl_lds16(const void* g, void* l) {
    __builtin_amdgcn_global_load_lds((const __attribute__((address_space(1))) unsigned int*)g,
                                     (__attribute__((address_space(3))) unsigned int*)l, 16, 0, 0);
}

// ---------------- root / R ----------------
__global__ void k_root(const float* __restrict__ x, const float* __restrict__ mask,
                       const float* __restrict__ w, const float* __restrict__ br,
                       float* __restrict__ R) {
    int wave = threadIdx.x >> 6, lane = threadIdx.x & 63;
    int row = blockIdx.x * 4 + wave;
    const float* xr = x + (size_t)row * DD;
    float s = 0.f;
#pragma unroll
    for (int k = 0; k < DD / 64; ++k) s += xr[k * 64 + lane] * w[k * 64 + lane];
    for (int off = 32; off; off >>= 1) s += __shfl_down(s, off, 64);
    if (lane == 0) {
        float m = mask[row] * -1e-4f;
        float rv = fmaxf(s + br[0] - 50.f * m, -40.f);
        R[row] = expf(rv);
    }
}

// ---------------- column sums of A (partials) ----------------
__global__ void k_colsum(const float* __restrict__ adj, const float* __restrict__ mask,
                         double* __restrict__ Lp) {
    int b = blockIdx.x, chunk = blockIdx.y;
    int j = threadIdx.x;
    float mj = mask[b * NN + j] * -1e-4f;
    const float* ab = adj + (size_t)b * NN * NN;
    double acc = 0.0;
    int i0 = chunk * 128;
    for (int i = i0; i < i0 + 128; ++i) {
        float mi = mask[b * NN + i] * -1e-4f;
        acc += (double)aval(ab[(size_t)i * NN + j], mi, mj);
    }
    Lp[((size_t)b * 4 + chunk) * NN + j] = acc;
}

// ---------------- build LL ----------------
template <typename T>
__global__ void k_build(const float* __restrict__ adj, const float* __restrict__ mask,
                        const float* __restrict__ R, const double* __restrict__ Lp,
                        T* __restrict__ M) {
    int b = blockIdx.x >> 9;
    int r = blockIdx.x & 511;
    int c = threadIdx.x;
    float mr = mask[b * NN + r] * -1e-4f;
    float mc = mask[b * NN + c] * -1e-4f;
    size_t idx = ((size_t)b * NN + r) * NN + c;
    float a = aval(adj[idx], mr, mc);
    T v;
    if (r == c) {
        const double* lp = Lp + (size_t)b * 4 * NN;
        double L = lp[c] + lp[NN + c] + lp[2 * NN + c] + lp[3 * NN + c];
        v = (T)(L - (double)a + (double)R[b * NN + c]);
    } else {
        v = (T)(-a);
    }
    M[idx] = v;
}

// ---------------- save column panel (fallback path only) ----------------
template <typename T>
__global__ void k_savecol(const T* __restrict__ M, T* __restrict__ Cb, int k0) {
    int t = threadIdx.x;
    int c = t & 63, rr = t >> 6;
    int row = blockIdx.x * 4 + rr;
    int b = row >> 9, i = row & 511;
    Cb[(size_t)row * KB + c] = M[((size_t)b * NN + i) * NN + k0 + c];
}

// ---------------- invert 64x64 pivot block ----------------
template <typename T>
__global__ void k_invblk(const T* __restrict__ M, T* __restrict__ Bb, int k0) {
    __shared__ double pr[KB];
    __shared__ double fv[KB];
    __shared__ double pvt;
    int b = blockIdx.x;
    int r = threadIdx.x & 63, q = threadIdx.x >> 6;
    double a[16];
    const T* Mb = M + ((size_t)b * NN + k0) * NN + k0;
#pragma unroll
    for (int c = 0; c < 16; ++c) a[c] = (double)Mb[(size_t)r * NN + q * 16 + c];
    for (int k = 0; k < KB; ++k) {
        int kq = k >> 4, kc = k & 15;
        if (r == k && q == kq) pvt = a[kc];
        __syncthreads();
        double ip = 1.0 / pvt;
        if (r == k) {
#pragma unroll
            for (int c = 0; c < 16; ++c) a[c] *= ip;
            if (q == kq) a[kc] = ip;
#pragma unroll
            for (int c = 0; c < 16; ++c) pr[q * 16 + c] = a[c];
        }
        if (r != k && q == kq) fv[r] = a[kc];
        __syncthreads();
        if (r != k) {
            double f = fv[r];
#pragma unroll
            for (int c = 0; c < 16; ++c) a[c] -= f * pr[q * 16 + c];
            if (q == kq) a[kc] = -f * ip;
        }
        __syncthreads();
    }
    T* Bo = Bb + (size_t)b * KB * KB;
#pragma unroll
    for (int c = 0; c < 16; ++c) Bo[r * KB + q * 16 + c] = (T)a[c];
}

// ---------------- MFMA pivot rows: M[step rows, jt] = Binv @ Mold ----------------
// f64 16x16x4 C/D map (HW-verified r4/r5): row = (lane>>4) + 4*reg, col = lane&15
__global__ __launch_bounds__(256) void k_piv_mfma(double* __restrict__ M,
                                                  const double* __restrict__ Bb, int step) {
    __shared__ double Ms[64][66];
    int b = blockIdx.y, jt = blockIdx.x;
    int t = threadIdx.x, w = t >> 6, l = t & 63;
    double* Mb = M + (size_t)b * NN * NN;
    double* Pr = Mb + (size_t)(step * 64) * NN;
    const double* Bi = Bb + (size_t)b * KB * KB;
    if (jt == step) {
        for (int i = 0; i < 16; ++i) {
            int c = i * 256 + t;
            int row = c >> 6, col = c & 63;
            Pr[(size_t)row * NN + step * 64 + col] = Bi[row * 64 + col];
        }
        return;
    }
    const double* Mg = Pr + jt * 64;
    for (int i = 0; i < 8; ++i) {
        int c = i * 256 + t;
        int row = c >> 5, ch = c & 31;
        f64x2 v = *(const f64x2*)(Mg + (size_t)row * NN + ch * 2);
        Ms[row][ch * 2] = v[0]; Ms[row][ch * 2 + 1] = v[1];
    }
    __syncthreads();
    int lr = l & 15, lg = l >> 4;
    double a[16];
#pragma unroll
    for (int kk = 0; kk < 16; ++kk) a[kk] = Bi[(w * 16 + lr) * 64 + kk * 4 + lg];
    double* Og = Pr + (size_t)(w * 16) * NN + jt * 64;
#pragma unroll
    for (int cf = 0; cf < 4; ++cf) {
        f64x4 acc = {0., 0., 0., 0.};
#pragma unroll
        for (int kk = 0; kk < 16; ++kk)
            acc = __builtin_amdgcn_mfma_f64_16x16x4f64(a[kk], Ms[kk * 4 + lg][cf * 16 + lr], acc, 0, 0, 0);
#pragma unroll
        for (int r = 0; r < 4; ++r) Og[(size_t)(lg + 4 * r) * NN + cf * 16 + lr] = acc[r];
    }
}

// ---------------- MFMA rank-64 update ----------------
template <int COLMODE>
__global__ __launch_bounds__(256) void k_upd_mfma(double* __restrict__ M, int step) {
    __shared__ double Cs[64][66];
    int b = blockIdx.y;
    int x = blockIdx.x;
    int it, jt;
    if (COLMODE) { it = x; jt = step; }
    else { it = x / 7; jt = x % 7; if (jt >= step) ++jt; }
    if (it >= step) ++it;
    int t = threadIdx.x, w = t >> 6, l = t & 63;
    double* Mb = M + (size_t)b * NN * NN;
    {
        const double* Cg = Mb + (size_t)(it * 64) * NN + step * 64;
        for (int i = 0; i < 8; ++i) {
            int c = i * 256 + t;
            int row = c >> 5, ch = c & 31;
            f64x2 v = *(const f64x2*)(Cg + (size_t)row * NN + ch * 2);
            Cs[row][ch * 2] = -v[0]; Cs[row][ch * 2 + 1] = -v[1];
        }
    }
    __syncthreads();
    int lr = l & 15, lg = l >> 4;
    double a[16];
#pragma unroll
    for (int kk = 0; kk < 16; ++kk) a[kk] = Cs[w * 16 + lr][kk * 4 + lg];
    const double* Rg = Mb + (size_t)(step * 64) * NN + jt * 64;
    double* Og = Mb + (size_t)(it * 64 + w * 16) * NN + jt * 64;
#pragma unroll
    for (int cf = 0; cf < 4; ++cf) {
        int c0 = cf * 16 + lr;
        f64x4 acc;
        if (COLMODE) {
            acc = (f64x4){0., 0., 0., 0.};
        } else {
#pragma unroll
            for (int r = 0; r < 4; ++r) acc[r] = Og[(size_t)(lg + 4 * r) * NN + c0];
        }
        const double* bp = Rg + (size_t)lg * NN + c0;
#pragma unroll
        for (int kk = 0; kk < 16; ++kk) {
            double bv = bp[(size_t)(kk * 4) * NN];
            acc = __builtin_amdgcn_mfma_f64_16x16x4f64(a[kk], bv, acc, 0, 0, 0);
        }
#pragma unroll
        for (int r = 0; r < 4; ++r) Og[(size_t)(lg + 4 * r) * NN + c0] = acc[r];
    }
}

// ---------------- scalar pivrows / update (fallback path only) ----------------
template <typename T>
__global__ void k_pivrows(T* __restrict__ M, const T* __restrict__ Bb, int k0) {
    __shared__ double Bi[KB][KB];
    __shared__ double Mt[KB][KB + 1];
    int b = blockIdx.x, jt = blockIdx.y * 64;
    const T* Bo = Bb + (size_t)b * KB * KB;
    T* Mb = M + ((size_t)b * NN + k0) * NN;
    int t = threadIdx.x;
    for (int e = t; e < KB * KB; e += 256) {
        int rr = e >> 6, cc = e & 63;
        Bi[rr][cc] = (double)Bo[e];
        Mt[rr][cc] = (double)Mb[(size_t)rr * NN + jt + cc];
    }
    __syncthreads();
    if (blockIdx.y == (unsigned)(k0 >> 6)) {
        for (int e = t; e < KB * KB; e += 256) {
            int rr = e >> 6, cc = e & 63;
            Mb[(size_t)rr * NN + jt + cc] = (T)Bi[rr][cc];
        }
        return;
    }
    int tx = t & 15, ty = t >> 4;
    double acc[4][4] = {};
    for (int k = 0; k < KB; ++k) {
        double av[4], bv[4];
#pragma unroll
        for (int u = 0; u < 4; ++u) { av[u] = Bi[ty * 4 + u][k]; bv[u] = Mt[k][tx * 4 + u]; }
#pragma unroll
        for (int u = 0; u < 4; ++u)
#pragma unroll
            for (int v = 0; v < 4; ++v) acc[u][v] += av[u] * bv[v];
    }
#pragma unroll
    for (int u = 0; u < 4; ++u)
#pragma unroll
        for (int v = 0; v < 4; ++v)
            Mb[(size_t)(ty * 4 + u) * NN + jt + tx * 4 + v] = (T)acc[u][v];
}

template <typename T>
__global__ void k_update(T* __restrict__ M, const T* __restrict__ Cb, int k0) {
    int step = k0 >> 6;
    int it = blockIdx.y;
    if (it == step) return;
    int b = blockIdx.x, jt = blockIdx.z;
    __shared__ double Ct[KB][KB + 1];
    __shared__ double Rt[KB][KB + 1];
    int t = threadIdx.x;
    const T* Cbb = Cb + ((size_t)b * NN + it * 64) * KB;
    const T* Rb  = M + ((size_t)b * NN + k0) * NN + jt * 64;
    for (int e = t; e < KB * KB; e += 256) {
        int rr = e >> 6, cc = e & 63;
        Ct[rr][cc] = (double)Cbb[(size_t)rr * KB + cc];
        Rt[rr][cc] = (double)Rb[(size_t)rr * NN + cc];
    }
    __syncthreads();
    int tx = t & 15, ty = t >> 4;
    double acc[4][4] = {};
    for (int k = 0; k < KB; ++k) {
        double av[4], bv[4];
#pragma unroll
        for (int u = 0; u < 4; ++u) { av[u] = Ct[ty * 4 + u][k]; bv[u] = Rt[k][tx * 4 + u]; }
#pragma unroll
        for (int u = 0; u < 4; ++u)
#pragma unroll
            for (int v = 0; v < 4; ++v) acc[u][v] += av[u] * bv[v];
    }
    T* Mo = M + ((size_t)b * NN + it * 64) * NN + jt * 64;
    bool blockcol = (jt == step);
#pragma unroll
    for (int u = 0; u < 4; ++u) {
        int row = ty * 4 + u;
#pragma unroll
        for (int v = 0; v < 4; ++v) {
            int col = tx * 4 + v;
            double val = (double)Mo[(size_t)row * NN + col] - acc[u][v];
            if (blockcol) val -= Ct[row][col];
            Mo[(size_t)row * NN + col] = (T)val;
        }
    }
}

// ---------------- diag extraction + BCE loss ----------------
template <typename T>
__global__ void k_dgloss(const T* __restrict__ M, const float* __restrict__ R,
                         const float* __restrict__ rlab, const int* __restrict__ rmask,
                         double* __restrict__ Dg, float* __restrict__ lossp) {
    int idx = blockIdx.x * 256 + threadIdx.x;
    int b = idx >> 9, n = idx & 511;
    double xv = (double)M[((size_t)b * NN + n) * NN + n];
    Dg[idx] = xv;
    float d0 = R[idx] * (float)xv;
    float lg = fminf(fmaxf(d0, 1e-5f), 1.f - 1e-5f);
    float rm = (float)rmask[idx];
    float lab = (rmask[idx] == 1) ? rlab[idx] : 0.f;
    float bce = -(lab * logf(lg) + (1.f - lab) * logf(1.f - lg));
    __shared__ double sm[256];
    sm[threadIdx.x] = (double)(bce * rm);
    __syncthreads();
    for (int s = 128; s; s >>= 1) {
        if (threadIdx.x < s) sm[threadIdx.x] += sm[threadIdx.x + s];
        __syncthreads();
    }
    if (threadIdx.x == 0) lossp[blockIdx.x] = (float)sm[0];
}

__global__ void k_lossfin(const float* __restrict__ lossp, float* __restrict__ outv) {
    __shared__ double sm[128];
    sm[threadIdx.x] = (double)lossp[threadIdx.x];
    __syncthreads();
    for (int s = 64; s; s >>= 1) {
        if (threadIdx.x < s) sm[threadIdx.x] += sm[threadIdx.x + s];
        __syncthreads();
    }
    if (threadIdx.x == 0) outv[0] = (float)(sm[0] / (double)(BB * NN));
}

// ---------------- d (fallback path) ----------------
template <typename T>
__global__ void k_d(const T* __restrict__ M, const double* __restrict__ Dg,
                    const float* __restrict__ adj, const float* __restrict__ mask,
                    float* __restrict__ dout) {
    int b = blockIdx.x, i0 = blockIdx.y * 64, j0 = blockIdx.z * 64;
    __shared__ double Xt[64][65];
    int t = threadIdx.x, ii = t & 63, jj0 = t >> 6;
    const T* Mb = M + (size_t)b * NN * NN;
    for (int jj = jj0; jj < 64; jj += 4)
        Xt[jj][ii] = (double)Mb[(size_t)(j0 + jj) * NN + i0 + ii];
    __syncthreads();
    int jc = t & 63, ir0 = t >> 6;
    float mj = mask[b * NN + j0 + jc] * -1e-4f;
    double dg = Dg[b * NN + j0 + jc];
    const float* ab = adj + (size_t)b * NN * NN;
    float* db = dout + (size_t)b * NN * NN;
    for (int ir = ir0; ir < 64; ir += 4) {
        int i = i0 + ir;
        float mi = mask[b * NN + i] * -1e-4f;
        float a = aval(ab[(size_t)i * NN + j0 + jc], mi, mj);
        db[(size_t)i * NN + j0 + jc] = a * (float)(dg - Xt[jc][ir]);
    }
}

// ---------------- d + transposed masked bf16 hi/lo attn ----------------
template <typename T>
__global__ void k_d2(const T* __restrict__ M, const double* __restrict__ Dg,
                     const float* __restrict__ adj, const float* __restrict__ mask,
                     float* __restrict__ dout,
                     unsigned short* __restrict__ ATh, unsigned short* __restrict__ ATl) {
    int b = blockIdx.x, i0 = blockIdx.y * 64, j0 = blockIdx.z * 64;
    __shared__ double Xt[64][65];
    __shared__ float dt[64][65];
    int t = threadIdx.x, ii = t & 63, jj0 = t >> 6;
    const T* Mb = M + (size_t)b * NN * NN;
    for (int jj = jj0; jj < 64; jj += 4)
        Xt[jj][ii] = (double)Mb[(size_t)(j0 + jj) * NN + i0 + ii];
    __syncthreads();
    int jc = t & 63, ir0 = t >> 6;
    float mj = mask[b * NN + j0 + jc] * -1e-4f;
    double dg = Dg[b * NN + j0 + jc];
    const float* ab = adj + (size_t)b * NN * NN;
    float* db = dout + (size_t)b * NN * NN;
    for (int ir = ir0; ir < 64; ir += 4) {
        int i = i0 + ir;
        float mi = mask[b * NN + i] * -1e-4f;
        float a = aval(ab[(size_t)i * NN + j0 + jc], mi, mj);
        float v = a * (float)(dg - Xt[jc][ir]);
        db[(size_t)i * NN + j0 + jc] = v;
        dt[ir][jc] = v;
    }
    __syncthreads();
    int ql = t >> 2, kq = t & 3;
    us8 vh0, vh1, vl0, vl1;
#pragma unroll
    for (int u = 0; u < 16; ++u) {
        int k = kq * 16 + u;
        float mk = mask[b * NN + i0 + k] * -1e-4f;
        float v = (mk > 0.5f) ? 0.f : dt[k][ql];
        unsigned short h = f2bf(v);
        unsigned short lo = f2bf(v - bf2f(h));
        if (u < 8) { vh0[u] = h; vl0[u] = lo; } else { vh1[u - 8] = h; vl1[u - 8] = lo; }
    }
    size_t ao = ((size_t)b * NN + j0 + ql) * NN + i0 + kq * 16;
    *(us8*)&ATh[ao] = vh0; *(us8*)&ATh[ao + 8] = vh1;
    *(us8*)&ATl[ao] = vl0; *(us8*)&ATl[ao + 8] = vl1;
}

// ---------------- x -> transposed bf16 hi/lo ----------------
__global__ void k_cvt_x(const float* __restrict__ x,
                        unsigned short* __restrict__ XTh, unsigned short* __restrict__ XTl) {
    int b = blockIdx.x, k0 = blockIdx.y * 64, c0 = blockIdx.z * 64;
    __shared__ float xs[64][65];
    int t = threadIdx.x;
#pragma unroll
    for (int rep = 0; rep < 16; ++rep) {
        int e = rep * 256 + t;
        int row = e >> 6, col = e & 63;
        xs[row][col] = x[((size_t)b * NN + k0 + row) * DD + c0 + col];
    }
    __syncthreads();
    int cl = t >> 2, kq = t & 3;
    us8 vh0, vh1, vl0, vl1;
#pragma unroll
    for (int u = 0; u < 16; ++u) {
        int k = kq * 16 + u;
        float v = xs[k][cl];
        unsigned short h = f2bf(v);
        unsigned short lo = f2bf(v - bf2f(h));
        if (u < 8) { vh0[u] = h; vl0[u] = lo; } else { vh1[u - 8] = h; vl1[u - 8] = lo; }
    }
    size_t ao = ((size_t)b * DD + c0 + cl) * NN + k0 + kq * 16;
    *(us8*)&XTh[ao] = vh0; *(us8*)&XTh[ao + 8] = vh1;
    *(us8*)&XTl[ao] = vl0; *(us8*)&XTl[ao + 8] = vl1;
}

// ---------------- context GEMM: fused single-pass bf16 MFMA ----------------
// Per K-tile of 32 stage Ah|Al and Xh|Xl interleaved per-row (8 granules of 8 bf16,
// XOR-swizzled), then issue Ah*Xh + Ah*Xl + Al*Xh. 4 tile-loads per K-tile vs 6.
__global__ __launch_bounds__(256) void k_ctx3(const unsigned short* __restrict__ ATh,
                                              const unsigned short* __restrict__ ATl,
                                              const unsigned short* __restrict__ XTh,
                                              const unsigned short* __restrict__ XTl,
                                              float* __restrict__ ctx) {
    __shared__ __align__(16) unsigned short ABs[128 * 64];
    __shared__ __align__(16) unsigned short Xs[128 * 64];
    int b = blockIdx.x;
    int bm = blockIdx.y * 128, bn = blockIdx.z * 128;
    int t = threadIdx.x, wid = t >> 6, lane = t & 63;
    f32x4 acc[4][4];
#pragma unroll
    for (int i = 0; i < 4; ++i)
#pragma unroll
        for (int j = 0; j < 4; ++j) acc[i][j] = (f32x4){0.f, 0.f, 0.f, 0.f};

    const unsigned short* Agh = ATh + ((size_t)b * NN + bm) * NN;
    const unsigned short* Agl = ATl + ((size_t)b * NN + bm) * NN;
    const unsigned short* Xgh = XTh + ((size_t)b * DD + bn) * NN;
    const unsigned short* Xgl = XTl + ((size_t)b * DD + bn) * NN;

    int m0 = (wid >> 1) * 64, n0 = (wid & 1) * 64;
    int kc = lane >> 4;

    for (int kt = 0; kt < 16; ++kt) {
        int ki = kt * 32;
        __syncthreads();
#pragma unroll
        for (int it2 = 0; it2 < 4; ++it2) {
            int chunk = it2 * 256 + wid * 64 + lane;
            int row = chunk >> 3;
            int gs = (chunk & 7) ^ (row & 7);
            const unsigned short* s = (gs < 4) ? Agh + (size_t)row * NN + ki + gs * 8
                                               : Agl + (size_t)row * NN + ki + (gs - 4) * 8;
            gl_lds16(s, &ABs[(it2 * 256 + wid * 64) * 8]);
        }
#pragma unroll
        for (int it2 = 0; it2 < 4; ++it2) {
            int chunk = it2 * 256 + wid * 64 + lane;
            int row = chunk >> 3;
            int gs = (chunk & 7) ^ (row & 7);
            const unsigned short* s = (gs < 4) ? Xgh + (size_t)row * NN + ki + gs * 8
                                               : Xgl + (size_t)row * NN + ki + (gs - 4) * 8;
            gl_lds16(s, &Xs[(it2 * 256 + wid * 64) * 8]);
        }
        __syncthreads();
        bf16x8 ah[4], al[4], xh[4], xl[4];
#pragma unroll
        for (int f = 0; f < 4; ++f) {
            int ar = m0 + f * 16 + (lane & 15);
            ah[f] = *(const bf16x8*)&ABs[(ar * 8 + (kc ^ (ar & 7))) * 8];
            al[f] = *(const bf16x8*)&ABs[(ar * 8 + ((kc | 4) ^ (ar & 7))) * 8];
            int br = n0 + f * 16 + (lane & 15);
            xh[f] = *(const bf16x8*)&Xs[(br * 8 + (kc ^ (br & 7))) * 8];
            xl[f] = *(const bf16x8*)&Xs[(br * 8 + ((kc | 4) ^ (br & 7))) * 8];
        }
#pragma unroll
        for (int fm = 0; fm < 4; ++fm)
#pragma unroll
            for (int fn = 0; fn < 4; ++fn) {
                acc[fm][fn] = __builtin_amdgcn_mfma_f32_16x16x32_bf16(ah[fm], xh[fn], acc[fm][fn], 0, 0, 0);
                acc[fm][fn] = __builtin_amdgcn_mfma_f32_16x16x32_bf16(ah[fm], xl[fn], acc[fm][fn], 0, 0, 0);
                acc[fm][fn] = __builtin_amdgcn_mfma_f32_16x16x32_bf16(al[fm], xh[fn], acc[fm][fn], 0, 0, 0);
            }
    }
    float* cb = ctx + ((size_t)b * NN + bm + m0) * DD + bn + n0;
#pragma unroll
    for (int fm = 0; fm < 4; ++fm)
#pragma unroll
        for (int fn = 0; fn < 4; ++fn)
#pragma unroll
            for (int r = 0; r < 4; ++r) {
                int row = fm * 16 + (lane >> 4) * 4 + r;
                int col = fn * 16 + (lane & 15);
                cb[(size_t)row * DD + col] = acc[fm][fn][r];
            }
}

// ---------------- context (fallback) ----------------
__global__ void k_ctx(const float* __restrict__ dmat, const float* __restrict__ x,
                      const float* __restrict__ mask, float* __restrict__ ctx) {
    int b = blockIdx.x, i0 = blockIdx.y * 64, c0 = blockIdx.z * 64;
    __shared__ float At[32][65];
    __shared__ float Xl[32][65];
    int t = threadIdx.x;
    int tx = t & 15, ty = t >> 4;
    float acc[4][4] = {};
    const float* db = dmat + (size_t)b * NN * NN;
    const float* xb = x + (size_t)b * NN * DD;
    int li = t & 63, lk = t >> 6;
    for (int kt = 0; kt < NN; kt += 32) {
#pragma unroll
        for (int rep = 0; rep < 8; ++rep) {
            int kk = lk + rep * 4;
            float mk = mask[b * NN + kt + kk] * -1e-4f;
            float v = db[(size_t)(kt + kk) * NN + i0 + li];
            At[kk][li] = (mk > 0.5f) ? 0.f : v;
            Xl[kk][li] = xb[(size_t)(kt + kk) * DD + c0 + li];
        }
        __syncthreads();
        for (int kk = 0; kk < 32; ++kk) {
            float av[4], bv[4];
#pragma unroll
            for (int u = 0; u < 4; ++u) { av[u] = At[kk][ty * 4 + u]; bv[u] = Xl[kk][tx * 4 + u]; }
#pragma unroll
            for (int u = 0; u < 4; ++u)
#pragma unroll
                for (int v = 0; v < 4; ++v) acc[u][v] += av[u] * bv[v];
        }
        __syncthreads();
    }
    float* cb = ctx + (size_t)b * NN * DD;
#pragma unroll
    for (int u = 0; u < 4; ++u)
#pragma unroll
        for (int v = 0; v < 4; ++v)
            cb[(size_t)(i0 + ty * 4 + u) * DD + c0 + tx * 4 + v] = acc[u][v];
}

// ---------------- drivers ----------------
template <typename T>
static void run_old(const float* x, const float* adj, const float* mask,
                    const float* rlab, const int* rmask, const float* w, const float* br,
                    float* ctx, float* dmat, float* lossout,
                    char* ws, hipStream_t stream) {
    size_t off = 0;
    T* M  = (T*)(ws + off); off += (size_t)BB * NN * NN * sizeof(T);
    T* Cb = (T*)(ws + off); off += (size_t)BB * NN * KB * sizeof(T);
    T* Bb = (T*)(ws + off); off += (size_t)BB * KB * KB * sizeof(T);
    double* Lp = (double*)(ws + off); off += (size_t)BB * 4 * NN * 8;
    float* Rf  = (float*)(ws + off);  off += (size_t)BB * NN * 4;
    double* Dg = (double*)(ws + off); off += (size_t)BB * NN * 8;
    float* lossp = (float*)(ws + off);

    k_root<<<BB * NN / 4, 256, 0, stream>>>(x, mask, w, br, Rf);
    k_colsum<<<dim3(BB, 4), 512, 0, stream>>>(adj, mask, Lp);
    k_build<T><<<BB * NN, 512, 0, stream>>>(adj, mask, Rf, Lp, M);
    for (int s = 0; s < NSTEP; ++s) {
        int k0 = s * KB;
        k_savecol<T><<<BB * NN / 4, 256, 0, stream>>>(M, Cb, k0);
        k_invblk<T><<<BB, 256, 0, stream>>>(M, Bb, k0);
        k_pivrows<T><<<dim3(BB, 8), 256, 0, stream>>>(M, Bb, k0);
        k_update<T><<<dim3(BB, 8, 8), 256, 0, stream>>>(M, Cb, k0);
    }
    k_dgloss<T><<<BB * NN / 256, 256, 0, stream>>>(M, Rf, rlab, rmask, Dg, lossp);
    k_lossfin<<<1, 128, 0, stream>>>(lossp, lossout);
    k_d<T><<<dim3(BB, 8, 8), 256, 0, stream>>>(M, Dg, adj, mask, dmat);
    k_ctx<<<dim3(BB, 8, 12), 256, 0, stream>>>(dmat, x, mask, ctx);
}

static void run_new(const float* x, const float* adj, const float* mask,
                    const float* rlab, const int* rmask, const float* w, const float* br,
                    float* ctx, float* dmat, float* lossout,
                    char* ws, hipStream_t stream) {
    size_t off = 0;
    double* M  = (double*)(ws + off); off += (size_t)BB * NN * NN * 8;
    double* Cb = (double*)(ws + off); off += (size_t)BB * NN * KB * 8;   // layout only
    double* Bb = (double*)(ws + off); off += (size_t)BB * KB * KB * 8;
    double* Lp = (double*)(ws + off); off += (size_t)BB * 4 * NN * 8;
    float* Rf  = (float*)(ws + off);  off += (size_t)BB * NN * 4;
    double* Dg = (double*)(ws + off); off += (size_t)BB * NN * 8;
    float* lossp = (float*)(ws + off); off += 4096;
    unsigned short* ATh = (unsigned short*)(ws + off); off += (size_t)BB * NN * NN * 2;
    unsigned short* ATl = (unsigned short*)(ws + off); off += (size_t)BB * NN * NN * 2;
    unsigned short* XTh = (unsigned short*)(ws);
    unsigned short* XTl = (unsigned short*)(ws + (size_t)BB * DD * NN * 2);
    (void)Cb;

    k_root<<<BB * NN / 4, 256, 0, stream>>>(x, mask, w, br, Rf);
    k_colsum<<<dim3(BB, 4), 512, 0, stream>>>(adj, mask, Lp);
    k_build<double><<<BB * NN, 512, 0, stream>>>(adj, mask, Rf, Lp, M);
    for (int s = 0; s < NSTEP; ++s) {
        k_invblk<double><<<BB, 256, 0, stream>>>(M, Bb, s * KB);
        k_piv_mfma<<<dim3(8, BB), 256, 0, stream>>>(M, Bb, s);
        k_upd_mfma<0><<<dim3(49, BB), 256, 0, stream>>>(M, s);
        k_upd_mfma<1><<<dim3(7, BB), 256, 0, stream>>>(M, s);
    }
    k_dgloss<double><<<BB * NN / 256, 256, 0, stream>>>(M, Rf, rlab, rmask, Dg, lossp);
    k_lossfin<<<1, 128, 0, stream>>>(lossp, lossout);
    k_d2<double><<<dim3(BB, 8, 8), 256, 0, stream>>>(M, Dg, adj, mask, dmat, ATh, ATl);
    k_cvt_x<<<dim3(BB, 8, 12), 256, 0, stream>>>(x, XTh, XTl);   // overwrites M region
    k_ctx3<<<dim3(BB, 4, 6), 256, 0, stream>>>(ATh, ATl, XTh, XTl, ctx);
}

extern "C" void kernel_launch(void* const* d_in, const int* in_sizes, int n_in,
                              void* d_out, int out_size, void* d_ws, size_t ws_size,
                              hipStream_t stream) {
    const float* x    = (const float*)d_in[0];
    const float* adj  = (const float*)d_in[1];
    const float* mask = (const float*)d_in[2];
    const float* rlab = (const float*)d_in[3];
    const int*   rmask= (const int*)d_in[4];
    const float* w    = (const float*)d_in[5];
    const float* br   = (const float*)d_in[6];
    float* out = (float*)d_out;
    float* ctx = out;
    float* dmat = out + (size_t)BB * NN * DD;
    float* lossout = dmat + (size_t)BB * NN * NN;
    char* ws = (char*)d_ws;

    size_t base = (size_t)BB * NN * NN * 8 + (size_t)BB * NN * KB * 8 + (size_t)BB * KB * KB * 8
                + (size_t)BB * 4 * NN * 8 + (size_t)BB * NN * 4 + (size_t)BB * NN * 8 + 4096;
    size_t need_new = base + (size_t)BB * NN * NN * 4;
    if (ws_size >= need_new)
        run_new(x, adj, mask, rlab, rmask, w, br, ctx, dmat, lossout, ws, stream);
    else if (ws_size >= base)
        run_old<double>(x, adj, mask, rlab, rmask, w, br, ctx, dmat, lossout, ws, stream);
    else
        run_old<float>(x, adj, mask, rlab, rmask, w, br, ctx, dmat, lossout, ws, stream);
}

// Round 7
// 1235.046 us; speedup vs baseline: 6.2292x; 1.1304x over previous
//
#include <hip/hip_runtime.h>
#include <cstdint>
#include <cstddef>

#define BB 64
#define NN 512
#define DD 768
#define KB 64
#define NSTEP (NN/KB)

typedef __bf16 bf16x8 __attribute__((ext_vector_type(8)));
typedef float f32x4 __attribute__((ext_vector_type(4)));
typedef unsigned short us8 __attribute__((ext_vector_type(8)));
typedef double f64x4 __attribute__((ext_vector_type(4)));
typedef double f64x2 __attribute__((ext_vector_type(2)));

__device__ __forceinline__ float aval(float adjv, float mi, float mj) {
    return expf(fmaxf(adjv - 50.f * (mi + mj), -40.f));
}

__device__ __forceinline__ unsigned short f2bf(float v) {
    union { float f; unsigned int u; } c; c.f = v;
    return (unsigned short)((c.u + 0x7fffu + ((c.u >> 16) & 1u)) >> 16);
}
__device__ __forceinline__ float bf2f(unsigned short h) {
    union { unsigned int u; float f; } c; c.u = ((unsigned int)h) << 16;
    return c.f;
}

__device__ __forceinline__ void gl_lds16(const void* g, void* l) {
    __builtin_amdgcn_global_load_lds((const __attribute__((address_space(1))) unsigned int*)g,
                                     (__attribute__((address_space(3))) unsigned int*)l, 16, 0, 0);
}

// ---------------- root / R ----------------
__global__ void k_root(const float* __restrict__ x, const float* __restrict__ mask,
                       const float* __restrict__ w, const float* __restrict__ br,
                       float* __restrict__ R) {
    int wave = threadIdx.x >> 6, lane = threadIdx.x & 63;
    int row = blockIdx.x * 4 + wave;
    const float* xr = x + (size_t)row * DD;
    float s = 0.f;
#pragma unroll
    for (int k = 0; k < DD / 64; ++k) s += xr[k * 64 + lane] * w[k * 64 + lane];
    for (int off = 32; off; off >>= 1) s += __shfl_down(s, off, 64);
    if (lane == 0) {
        float m = mask[row] * -1e-4f;
        float rv = fmaxf(s + br[0] - 50.f * m, -40.f);
        R[row] = expf(rv);
    }
}

// ---------------- column sums of A (partials) ----------------
__global__ void k_colsum(const float* __restrict__ adj, const float* __restrict__ mask,
                         double* __restrict__ Lp) {
    int b = blockIdx.x, chunk = blockIdx.y;
    int j = threadIdx.x;
    float mj = mask[b * NN + j] * -1e-4f;
    const float* ab = adj + (size_t)b * NN * NN;
    double acc = 0.0;
    int i0 = chunk * 128;
    for (int i = i0; i < i0 + 128; ++i) {
        float mi = mask[b * NN + i] * -1e-4f;
        acc += (double)aval(ab[(size_t)i * NN + j], mi, mj);
    }
    Lp[((size_t)b * 4 + chunk) * NN + j] = acc;
}

// ---------------- build LL ----------------
template <typename T>
__global__ void k_build(const float* __restrict__ adj, const float* __restrict__ mask,
                        const float* __restrict__ R, const double* __restrict__ Lp,
                        T* __restrict__ M) {
    int b = blockIdx.x >> 9;
    int r = blockIdx.x & 511;
    int c = threadIdx.x;
    float mr = mask[b * NN + r] * -1e-4f;
    float mc = mask[b * NN + c] * -1e-4f;
    size_t idx = ((size_t)b * NN + r) * NN + c;
    float a = aval(adj[idx], mr, mc);
    T v;
    if (r == c) {
        const double* lp = Lp + (size_t)b * 4 * NN;
        double L = lp[c] + lp[NN + c] + lp[2 * NN + c] + lp[3 * NN + c];
        v = (T)(L - (double)a + (double)R[b * NN + c]);
    } else {
        v = (T)(-a);
    }
    M[idx] = v;
}

// ---------------- save column panel (fallback path only) ----------------
template <typename T>
__global__ void k_savecol(const T* __restrict__ M, T* __restrict__ Cb, int k0) {
    int t = threadIdx.x;
    int c = t & 63, rr = t >> 6;
    int row = blockIdx.x * 4 + rr;
    int b = row >> 9, i = row & 511;
    Cb[(size_t)row * KB + c] = M[((size_t)b * NN + i) * NN + k0 + c];
}

// ---------------- invert 64x64 pivot block ----------------
template <typename T>
__global__ void k_invblk(const T* __restrict__ M, T* __restrict__ Bb, int k0) {
    __shared__ double pr[KB];
    __shared__ double fv[KB];
    __shared__ double pvt;
    int b = blockIdx.x;
    int r = threadIdx.x & 63, q = threadIdx.x >> 6;
    double a[16];
    const T* Mb = M + ((size_t)b * NN + k0) * NN + k0;
#pragma unroll
    for (int c = 0; c < 16; ++c) a[c] = (double)Mb[(size_t)r * NN + q * 16 + c];
    for (int k = 0; k < KB; ++k) {
        int kq = k >> 4, kc = k & 15;
        if (r == k && q == kq) pvt = a[kc];
        __syncthreads();
        double ip = 1.0 / pvt;
        if (r == k) {
#pragma unroll
            for (int c = 0; c < 16; ++c) a[c] *= ip;
            if (q == kq) a[kc] = ip;
#pragma unroll
            for (int c = 0; c < 16; ++c) pr[q * 16 + c] = a[c];
        }
        if (r != k && q == kq) fv[r] = a[kc];
        __syncthreads();
        if (r != k) {
            double f = fv[r];
#pragma unroll
            for (int c = 0; c < 16; ++c) a[c] -= f * pr[q * 16 + c];
            if (q == kq) a[kc] = -f * ip;
        }
        __syncthreads();
    }
    T* Bo = Bb + (size_t)b * KB * KB;
#pragma unroll
    for (int c = 0; c < 16; ++c) Bo[r * KB + q * 16 + c] = (T)a[c];
}

// ---------------- MFMA pivot rows: M[step rows, jt] = Binv @ Mold ----------------
// f64 16x16x4 C/D map (HW-verified r4/r5): row = (lane>>4) + 4*reg, col = lane&15
__global__ __launch_bounds__(256) void k_piv_mfma(double* __restrict__ M,
                                                  const double* __restrict__ Bb, int step) {
    __shared__ double Ms[64][66];
    int b = blockIdx.y, jt = blockIdx.x;
    int t = threadIdx.x, w = t >> 6, l = t & 63;
    double* Mb = M + (size_t)b * NN * NN;
    double* Pr = Mb + (size_t)(step * 64) * NN;
    const double* Bi = Bb + (size_t)b * KB * KB;
    if (jt == step) {
        for (int i = 0; i < 16; ++i) {
            int c = i * 256 + t;
            int row = c >> 6, col = c & 63;
            Pr[(size_t)row * NN + step * 64 + col] = Bi[row * 64 + col];
        }
        return;
    }
    const double* Mg = Pr + jt * 64;
    for (int i = 0; i < 8; ++i) {
        int c = i * 256 + t;
        int row = c >> 5, ch = c & 31;
        f64x2 v = *(const f64x2*)(Mg + (size_t)row * NN + ch * 2);
        Ms[row][ch * 2] = v[0]; Ms[row][ch * 2 + 1] = v[1];
    }
    __syncthreads();
    int lr = l & 15, lg = l >> 4;
    double a[16];
#pragma unroll
    for (int kk = 0; kk < 16; ++kk) a[kk] = Bi[(w * 16 + lr) * 64 + kk * 4 + lg];
    double* Og = Pr + (size_t)(w * 16) * NN + jt * 64;
#pragma unroll
    for (int cf = 0; cf < 4; ++cf) {
        f64x4 acc = {0., 0., 0., 0.};
#pragma unroll
        for (int kk = 0; kk < 16; ++kk)
            acc = __builtin_amdgcn_mfma_f64_16x16x4f64(a[kk], Ms[kk * 4 + lg][cf * 16 + lr], acc, 0, 0, 0);
#pragma unroll
        for (int r = 0; r < 4; ++r) Og[(size_t)(lg + 4 * r) * NN + cf * 16 + lr] = acc[r];
    }
}

// ---------------- fused MFMA rank-64 update (upd0 + upd1) ----------------
// grid (14, BB): x>>1 = it-slot (7 non-step rows), x&1 = jt-half.
// Block: stage -C(it) once -> A frags in regs; loop jt half staging R(step,jt) in
// reused LDS; half==1 block finishes with M(it,step) = (-C)*Binv.
__global__ __launch_bounds__(256) void k_upd2(double* __restrict__ M,
                                              const double* __restrict__ Bb, int step) {
    __shared__ double Ts[64][66];
    int b = blockIdx.y;
    int x = blockIdx.x;
    int it = x >> 1, half = x & 1;
    if (it >= step) ++it;
    int t = threadIdx.x, w = t >> 6, l = t & 63;
    double* Mb = M + (size_t)b * NN * NN;
    // stage -C tile (rows it*64.., cols step*64..)
    {
        const double* Cg = Mb + (size_t)(it * 64) * NN + step * 64;
        for (int i = 0; i < 8; ++i) {
            int c = i * 256 + t;
            int row = c >> 5, ch = c & 31;
            f64x2 v = *(const f64x2*)(Cg + (size_t)row * NN + ch * 2);
            Ts[row][ch * 2] = -v[0]; Ts[row][ch * 2 + 1] = -v[1];
        }
    }
    __syncthreads();
    int lr = l & 15, lg = l >> 4;
    double a[16];
#pragma unroll
    for (int kk = 0; kk < 16; ++kk) a[kk] = Ts[w * 16 + lr][kk * 4 + lg];
    __syncthreads();
    int nj = half ? 3 : 4;
    for (int jj = 0; jj < nj; ++jj) {
        int jtidx = half ? 4 + jj : jj;        // index into 7 non-step cols
        int jt = (jtidx < step) ? jtidx : jtidx + 1;
        // stage R(step, jt) into reused LDS
        const double* Rg = Mb + (size_t)(step * 64) * NN + jt * 64;
        for (int i = 0; i < 8; ++i) {
            int c = i * 256 + t;
            int row = c >> 5, ch = c & 31;
            f64x2 v = *(const f64x2*)(Rg + (size_t)row * NN + ch * 2);
            Ts[row][ch * 2] = v[0]; Ts[row][ch * 2 + 1] = v[1];
        }
        __syncthreads();
        double* Og = Mb + (size_t)(it * 64 + w * 16) * NN + jt * 64;
#pragma unroll
        for (int cf = 0; cf < 4; ++cf) {
            int c0 = cf * 16 + lr;
            f64x4 acc;
#pragma unroll
            for (int r = 0; r < 4; ++r) acc[r] = Og[(size_t)(lg + 4 * r) * NN + c0];
#pragma unroll
            for (int kk = 0; kk < 16; ++kk)
                acc = __builtin_amdgcn_mfma_f64_16x16x4f64(a[kk], Ts[kk * 4 + lg][c0], acc, 0, 0, 0);
#pragma unroll
            for (int r = 0; r < 4; ++r) Og[(size_t)(lg + 4 * r) * NN + c0] = acc[r];
        }
        __syncthreads();
    }
    if (half) {
        // upd1: M(it, step) = (-C) * Binv
        const double* Bi = Bb + (size_t)b * KB * KB;
        for (int i = 0; i < 8; ++i) {
            int c = i * 256 + t;
            int row = c >> 5, ch = c & 31;
            f64x2 v = *(const f64x2*)(Bi + row * 64 + ch * 2);
            Ts[row][ch * 2] = v[0]; Ts[row][ch * 2 + 1] = v[1];
        }
        __syncthreads();
        double* Og = Mb + (size_t)(it * 64 + w * 16) * NN + step * 64;
#pragma unroll
        for (int cf = 0; cf < 4; ++cf) {
            int c0 = cf * 16 + lr;
            f64x4 acc = {0., 0., 0., 0.};
#pragma unroll
            for (int kk = 0; kk < 16; ++kk)
                acc = __builtin_amdgcn_mfma_f64_16x16x4f64(a[kk], Ts[kk * 4 + lg][c0], acc, 0, 0, 0);
#pragma unroll
            for (int r = 0; r < 4; ++r) Og[(size_t)(lg + 4 * r) * NN + c0] = acc[r];
        }
    }
}

// ---------------- scalar pivrows / update (fallback path only) ----------------
template <typename T>
__global__ void k_pivrows(T* __restrict__ M, const T* __restrict__ Bb, int k0) {
    __shared__ double Bi[KB][KB];
    __shared__ double Mt[KB][KB + 1];
    int b = blockIdx.x, jt = blockIdx.y * 64;
    const T* Bo = Bb + (size_t)b * KB * KB;
    T* Mb = M + ((size_t)b * NN + k0) * NN;
    int t = threadIdx.x;
    for (int e = t; e < KB * KB; e += 256) {
        int rr = e >> 6, cc = e & 63;
        Bi[rr][cc] = (double)Bo[e];
        Mt[rr][cc] = (double)Mb[(size_t)rr * NN + jt + cc];
    }
    __syncthreads();
    if (blockIdx.y == (unsigned)(k0 >> 6)) {
        for (int e = t; e < KB * KB; e += 256) {
            int rr = e >> 6, cc = e & 63;
            Mb[(size_t)rr * NN + jt + cc] = (T)Bi[rr][cc];
        }
        return;
    }
    int tx = t & 15, ty = t >> 4;
    double acc[4][4] = {};
    for (int k = 0; k < KB; ++k) {
        double av[4], bv[4];
#pragma unroll
        for (int u = 0; u < 4; ++u) { av[u] = Bi[ty * 4 + u][k]; bv[u] = Mt[k][tx * 4 + u]; }
#pragma unroll
        for (int u = 0; u < 4; ++u)
#pragma unroll
            for (int v = 0; v < 4; ++v) acc[u][v] += av[u] * bv[v];
    }
#pragma unroll
    for (int u = 0; u < 4; ++u)
#pragma unroll
        for (int v = 0; v < 4; ++v)
            Mb[(size_t)(ty * 4 + u) * NN + jt + tx * 4 + v] = (T)acc[u][v];
}

template <typename T>
__global__ void k_update(T* __restrict__ M, const T* __restrict__ Cb, int k0) {
    int step = k0 >> 6;
    int it = blockIdx.y;
    if (it == step) return;
    int b = blockIdx.x, jt = blockIdx.z;
    __shared__ double Ct[KB][KB + 1];
    __shared__ double Rt[KB][KB + 1];
    int t = threadIdx.x;
    const T* Cbb = Cb + ((size_t)b * NN + it * 64) * KB;
    const T* Rb  = M + ((size_t)b * NN + k0) * NN + jt * 64;
    for (int e = t; e < KB * KB; e += 256) {
        int rr = e >> 6, cc = e & 63;
        Ct[rr][cc] = (double)Cbb[(size_t)rr * KB + cc];
        Rt[rr][cc] = (double)Rb[(size_t)rr * NN + cc];
    }
    __syncthreads();
    int tx = t & 15, ty = t >> 4;
    double acc[4][4] = {};
    for (int k = 0; k < KB; ++k) {
        double av[4], bv[4];
#pragma unroll
        for (int u = 0; u < 4; ++u) { av[u] = Ct[ty * 4 + u][k]; bv[u] = Rt[k][tx * 4 + u]; }
#pragma unroll
        for (int u = 0; u < 4; ++u)
#pragma unroll
            for (int v = 0; v < 4; ++v) acc[u][v] += av[u] * bv[v];
    }
    T* Mo = M + ((size_t)b * NN + it * 64) * NN + jt * 64;
    bool blockcol = (jt == step);
#pragma unroll
    for (int u = 0; u < 4; ++u) {
        int row = ty * 4 + u;
#pragma unroll
        for (int v = 0; v < 4; ++v) {
            int col = tx * 4 + v;
            double val = (double)Mo[(size_t)row * NN + col] - acc[u][v];
            if (blockcol) val -= Ct[row][col];
            Mo[(size_t)row * NN + col] = (T)val;
        }
    }
}

// ---------------- diag extraction + BCE loss ----------------
template <typename T>
__global__ void k_dgloss(const T* __restrict__ M, const float* __restrict__ R,
                         const float* __restrict__ rlab, const int* __restrict__ rmask,
                         double* __restrict__ Dg, float* __restrict__ lossp) {
    int idx = blockIdx.x * 256 + threadIdx.x;
    int b = idx >> 9, n = idx & 511;
    double xv = (double)M[((size_t)b * NN + n) * NN + n];
    Dg[idx] = xv;
    float d0 = R[idx] * (float)xv;
    float lg = fminf(fmaxf(d0, 1e-5f), 1.f - 1e-5f);
    float rm = (float)rmask[idx];
    float lab = (rmask[idx] == 1) ? rlab[idx] : 0.f;
    float bce = -(lab * logf(lg) + (1.f - lab) * logf(1.f - lg));
    __shared__ double sm[256];
    sm[threadIdx.x] = (double)(bce * rm);
    __syncthreads();
    for (int s = 128; s; s >>= 1) {
        if (threadIdx.x < s) sm[threadIdx.x] += sm[threadIdx.x + s];
        __syncthreads();
    }
    if (threadIdx.x == 0) lossp[blockIdx.x] = (float)sm[0];
}

__global__ void k_lossfin(const float* __restrict__ lossp, float* __restrict__ outv) {
    __shared__ double sm[128];
    sm[threadIdx.x] = (double)lossp[threadIdx.x];
    __syncthreads();
    for (int s = 64; s; s >>= 1) {
        if (threadIdx.x < s) sm[threadIdx.x] += sm[threadIdx.x + s];
        __syncthreads();
    }
    if (threadIdx.x == 0) outv[0] = (float)(sm[0] / (double)(BB * NN));
}

// ---------------- d (fallback path) ----------------
template <typename T>
__global__ void k_d(const T* __restrict__ M, const double* __restrict__ Dg,
                    const float* __restrict__ adj, const float* __restrict__ mask,
                    float* __restrict__ dout) {
    int b = blockIdx.x, i0 = blockIdx.y * 64, j0 = blockIdx.z * 64;
    __shared__ double Xt[64][65];
    int t = threadIdx.x, ii = t & 63, jj0 = t >> 6;
    const T* Mb = M + (size_t)b * NN * NN;
    for (int jj = jj0; jj < 64; jj += 4)
        Xt[jj][ii] = (double)Mb[(size_t)(j0 + jj) * NN + i0 + ii];
    __syncthreads();
    int jc = t & 63, ir0 = t >> 6;
    float mj = mask[b * NN + j0 + jc] * -1e-4f;
    double dg = Dg[b * NN + j0 + jc];
    const float* ab = adj + (size_t)b * NN * NN;
    float* db = dout + (size_t)b * NN * NN;
    for (int ir = ir0; ir < 64; ir += 4) {
        int i = i0 + ir;
        float mi = mask[b * NN + i] * -1e-4f;
        float a = aval(ab[(size_t)i * NN + j0 + jc], mi, mj);
        db[(size_t)i * NN + j0 + jc] = a * (float)(dg - Xt[jc][ir]);
    }
}

// ---------------- d + transposed masked bf16 hi/lo attn (f32 X staging) ----------------
template <typename T>
__global__ void k_d2(const T* __restrict__ M, const double* __restrict__ Dg,
                     const float* __restrict__ adj, const float* __restrict__ mask,
                     float* __restrict__ dout,
                     unsigned short* __restrict__ ATh, unsigned short* __restrict__ ATl) {
    int b = blockIdx.x, i0 = blockIdx.y * 64, j0 = blockIdx.z * 64;
    __shared__ float Xt[64][65];
    __shared__ float dt[64][65];
    int t = threadIdx.x, ii = t & 63, jj0 = t >> 6;
    const T* Mb = M + (size_t)b * NN * NN;
    for (int jj = jj0; jj < 64; jj += 4)
        Xt[jj][ii] = (float)Mb[(size_t)(j0 + jj) * NN + i0 + ii];
    __syncthreads();
    int jc = t & 63, ir0 = t >> 6;
    float mj = mask[b * NN + j0 + jc] * -1e-4f;
    double dg = Dg[b * NN + j0 + jc];
    const float* ab = adj + (size_t)b * NN * NN;
    float* db = dout + (size_t)b * NN * NN;
    for (int ir = ir0; ir < 64; ir += 4) {
        int i = i0 + ir;
        float mi = mask[b * NN + i] * -1e-4f;
        float a = aval(ab[(size_t)i * NN + j0 + jc], mi, mj);
        float v = a * (float)(dg - (double)Xt[jc][ir]);
        db[(size_t)i * NN + j0 + jc] = v;
        dt[ir][jc] = v;
    }
    __syncthreads();
    int ql = t >> 2, kq = t & 3;
    us8 vh0, vh1, vl0, vl1;
#pragma unroll
    for (int u = 0; u < 16; ++u) {
        int k = kq * 16 + u;
        float mk = mask[b * NN + i0 + k] * -1e-4f;
        float v = (mk > 0.5f) ? 0.f : dt[k][ql];
        unsigned short h = f2bf(v);
        unsigned short lo = f2bf(v - bf2f(h));
        if (u < 8) { vh0[u] = h; vl0[u] = lo; } else { vh1[u - 8] = h; vl1[u - 8] = lo; }
    }
    size_t ao = ((size_t)b * NN + j0 + ql) * NN + i0 + kq * 16;
    *(us8*)&ATh[ao] = vh0; *(us8*)&ATh[ao + 8] = vh1;
    *(us8*)&ATl[ao] = vl0; *(us8*)&ATl[ao + 8] = vl1;
}

// ---------------- x -> transposed bf16 hi/lo ----------------
__global__ void k_cvt_x(const float* __restrict__ x,
                        unsigned short* __restrict__ XTh, unsigned short* __restrict__ XTl) {
    int b = blockIdx.x, k0 = blockIdx.y * 64, c0 = blockIdx.z * 64;
    __shared__ float xs[64][65];
    int t = threadIdx.x;
#pragma unroll
    for (int rep = 0; rep < 16; ++rep) {
        int e = rep * 256 + t;
        int row = e >> 6, col = e & 63;
        xs[row][col] = x[((size_t)b * NN + k0 + row) * DD + c0 + col];
    }
    __syncthreads();
    int cl = t >> 2, kq = t & 3;
    us8 vh0, vh1, vl0, vl1;
#pragma unroll
    for (int u = 0; u < 16; ++u) {
        int k = kq * 16 + u;
        float v = xs[k][cl];
        unsigned short h = f2bf(v);
        unsigned short lo = f2bf(v - bf2f(h));
        if (u < 8) { vh0[u] = h; vl0[u] = lo; } else { vh1[u - 8] = h; vl1[u - 8] = lo; }
    }
    size_t ao = ((size_t)b * DD + c0 + cl) * NN + k0 + kq * 16;
    *(us8*)&XTh[ao] = vh0; *(us8*)&XTh[ao + 8] = vh1;
    *(us8*)&XTl[ao] = vl0; *(us8*)&XTl[ao + 8] = vl1;
}

// ---------------- context GEMM: fused single-pass bf16 MFMA ----------------
__global__ __launch_bounds__(256) void k_ctx3(const unsigned short* __restrict__ ATh,
                                              const unsigned short* __restrict__ ATl,
                                              const unsigned short* __restrict__ XTh,
                                              const unsigned short* __restrict__ XTl,
                                              float* __restrict__ ctx) {
    __shared__ __align__(16) unsigned short ABs[128 * 64];
    __shared__ __align__(16) unsigned short Xs[128 * 64];
    int b = blockIdx.x;
    int bm = blockIdx.y * 128, bn = blockIdx.z * 128;
    int t = threadIdx.x, wid = t >> 6, lane = t & 63;
    f32x4 acc[4][4];
#pragma unroll
    for (int i = 0; i < 4; ++i)
#pragma unroll
        for (int j = 0; j < 4; ++j) acc[i][j] = (f32x4){0.f, 0.f, 0.f, 0.f};

    const unsigned short* Agh = ATh + ((size_t)b * NN + bm) * NN;
    const unsigned short* Agl = ATl + ((size_t)b * NN + bm) * NN;
    const unsigned short* Xgh = XTh + ((size_t)b * DD + bn) * NN;
    const unsigned short* Xgl = XTl + ((size_t)b * DD + bn) * NN;

    int m0 = (wid >> 1) * 64, n0 = (wid & 1) * 64;
    int kc = lane >> 4;

    for (int kt = 0; kt < 16; ++kt) {
        int ki = kt * 32;
        __syncthreads();
#pragma unroll
        for (int it2 = 0; it2 < 4; ++it2) {
            int chunk = it2 * 256 + wid * 64 + lane;
            int row = chunk >> 3;
            int gs = (chunk & 7) ^ (row & 7);
            const unsigned short* s = (gs < 4) ? Agh + (size_t)row * NN + ki + gs * 8
                                               : Agl + (size_t)row * NN + ki + (gs - 4) * 8;
            gl_lds16(s, &ABs[(it2 * 256 + wid * 64) * 8]);
        }
#pragma unroll
        for (int it2 = 0; it2 < 4; ++it2) {
            int chunk = it2 * 256 + wid * 64 + lane;
            int row = chunk >> 3;
            int gs = (chunk & 7) ^ (row & 7);
            const unsigned short* s = (gs < 4) ? Xgh + (size_t)row * NN + ki + gs * 8
                                               : Xgl + (size_t)row * NN + ki + (gs - 4) * 8;
            gl_lds16(s, &Xs[(it2 * 256 + wid * 64) * 8]);
        }
        __syncthreads();
        bf16x8 ah[4], al[4], xh[4], xl[4];
#pragma unroll
        for (int f = 0; f < 4; ++f) {
            int ar = m0 + f * 16 + (lane & 15);
            ah[f] = *(const bf16x8*)&ABs[(ar * 8 + (kc ^ (ar & 7))) * 8];
            al[f] = *(const bf16x8*)&ABs[(ar * 8 + ((kc | 4) ^ (ar & 7))) * 8];
            int br = n0 + f * 16 + (lane & 15);
            xh[f] = *(const bf16x8*)&Xs[(br * 8 + (kc ^ (br & 7))) * 8];
            xl[f] = *(const bf16x8*)&Xs[(br * 8 + ((kc | 4) ^ (br & 7))) * 8];
        }
#pragma unroll
        for (int fm = 0; fm < 4; ++fm)
#pragma unroll
            for (int fn = 0; fn < 4; ++fn) {
                acc[fm][fn] = __builtin_amdgcn_mfma_f32_16x16x32_bf16(ah[fm], xh[fn], acc[fm][fn], 0, 0, 0);
                acc[fm][fn] = __builtin_amdgcn_mfma_f32_16x16x32_bf16(ah[fm], xl[fn], acc[fm][fn], 0, 0, 0);
                acc[fm][fn] = __builtin_amdgcn_mfma_f32_16x16x32_bf16(al[fm], xh[fn], acc[fm][fn], 0, 0, 0);
            }
    }
    float* cb = ctx + ((size_t)b * NN + bm + m0) * DD + bn + n0;
#pragma unroll
    for (int fm = 0; fm < 4; ++fm)
#pragma unroll
        for (int fn = 0; fn < 4; ++fn)
#pragma unroll
            for (int r = 0; r < 4; ++r) {
                int row = fm * 16 + (lane >> 4) * 4 + r;
                int col = fn * 16 + (lane & 15);
                cb[(size_t)row * DD + col] = acc[fm][fn][r];
            }
}

// ---------------- context (fallback) ----------------
__global__ void k_ctx(const float* __restrict__ dmat, const float* __restrict__ x,
                      const float* __restrict__ mask, float* __restrict__ ctx) {
    int b = blockIdx.x, i0 = blockIdx.y * 64, c0 = blockIdx.z * 64;
    __shared__ float At[32][65];
    __shared__ float Xl[32][65];
    int t = threadIdx.x;
    int tx = t & 15, ty = t >> 4;
    float acc[4][4] = {};
    const float* db = dmat + (size_t)b * NN * NN;
    const float* xb = x + (size_t)b * NN * DD;
    int li = t & 63, lk = t >> 6;
    for (int kt = 0; kt < NN; kt += 32) {
#pragma unroll
        for (int rep = 0; rep < 8; ++rep) {
            int kk = lk + rep * 4;
            float mk = mask[b * NN + kt + kk] * -1e-4f;
            float v = db[(size_t)(kt + kk) * NN + i0 + li];
            At[kk][li] = (mk > 0.5f) ? 0.f : v;
            Xl[kk][li] = xb[(size_t)(kt + kk) * DD + c0 + li];
        }
        __syncthreads();
        for (int kk = 0; kk < 32; ++kk) {
            float av[4], bv[4];
#pragma unroll
            for (int u = 0; u < 4; ++u) { av[u] = At[kk][ty * 4 + u]; bv[u] = Xl[kk][tx * 4 + u]; }
#pragma unroll
            for (int u = 0; u < 4; ++u)
#pragma unroll
                for (int v = 0; v < 4; ++v) acc[u][v] += av[u] * bv[v];
        }
        __syncthreads();
    }
    float* cb = ctx + (size_t)b * NN * DD;
#pragma unroll
    for (int u = 0; u < 4; ++u)
#pragma unroll
        for (int v = 0; v < 4; ++v)
            cb[(size_t)(i0 + ty * 4 + u) * DD + c0 + tx * 4 + v] = acc[u][v];
}

// ---------------- drivers ----------------
template <typename T>
static void run_old(const float* x, const float* adj, const float* mask,
                    const float* rlab, const int* rmask, const float* w, const float* br,
                    float* ctx, float* dmat, float* lossout,
                    char* ws, hipStream_t stream) {
    size_t off = 0;
    T* M  = (T*)(ws + off); off += (size_t)BB * NN * NN * sizeof(T);
    T* Cb = (T*)(ws + off); off += (size_t)BB * NN * KB * sizeof(T);
    T* Bb = (T*)(ws + off); off += (size_t)BB * KB * KB * sizeof(T);
    double* Lp = (double*)(ws + off); off += (size_t)BB * 4 * NN * 8;
    float* Rf  = (float*)(ws + off);  off += (size_t)BB * NN * 4;
    double* Dg = (double*)(ws + off); off += (size_t)BB * NN * 8;
    float* lossp = (float*)(ws + off);

    k_root<<<BB * NN / 4, 256, 0, stream>>>(x, mask, w, br, Rf);
    k_colsum<<<dim3(BB, 4), 512, 0, stream>>>(adj, mask, Lp);
    k_build<T><<<BB * NN, 512, 0, stream>>>(adj, mask, Rf, Lp, M);
    for (int s = 0; s < NSTEP; ++s) {
        int k0 = s * KB;
        k_savecol<T><<<BB * NN / 4, 256, 0, stream>>>(M, Cb, k0);
        k_invblk<T><<<BB, 256, 0, stream>>>(M, Bb, k0);
        k_pivrows<T><<<dim3(BB, 8), 256, 0, stream>>>(M, Bb, k0);
        k_update<T><<<dim3(BB, 8, 8), 256, 0, stream>>>(M, Cb, k0);
    }
    k_dgloss<T><<<BB * NN / 256, 256, 0, stream>>>(M, Rf, rlab, rmask, Dg, lossp);
    k_lossfin<<<1, 128, 0, stream>>>(lossp, lossout);
    k_d<T><<<dim3(BB, 8, 8), 256, 0, stream>>>(M, Dg, adj, mask, dmat);
    k_ctx<<<dim3(BB, 8, 12), 256, 0, stream>>>(dmat, x, mask, ctx);
}

static void run_new(const float* x, const float* adj, const float* mask,
                    const float* rlab, const int* rmask, const float* w, const float* br,
                    float* ctx, float* dmat, float* lossout,
                    char* ws, hipStream_t stream) {
    size_t off = 0;
    double* M  = (double*)(ws + off); off += (size_t)BB * NN * NN * 8;
    double* Cb = (double*)(ws + off); off += (size_t)BB * NN * KB * 8;   // layout only
    double* Bb = (double*)(ws + off); off += (size_t)BB * KB * KB * 8;
    double* Lp = (double*)(ws + off); off += (size_t)BB * 4 * NN * 8;
    float* Rf  = (float*)(ws + off);  off += (size_t)BB * NN * 4;
    double* Dg = (double*)(ws + off); off += (size_t)BB * NN * 8;
    float* lossp = (float*)(ws + off); off += 4096;
    unsigned short* ATh = (unsigned short*)(ws + off); off += (size_t)BB * NN * NN * 2;
    unsigned short* ATl = (unsigned short*)(ws + off); off += (size_t)BB * NN * NN * 2;
    unsigned short* XTh = (unsigned short*)(ws);
    unsigned short* XTl = (unsigned short*)(ws + (size_t)BB * DD * NN * 2);
    (void)Cb;

    k_root<<<BB * NN / 4, 256, 0, stream>>>(x, mask, w, br, Rf);
    k_colsum<<<dim3(BB, 4), 512, 0, stream>>>(adj, mask, Lp);
    k_build<double><<<BB * NN, 512, 0, stream>>>(adj, mask, Rf, Lp, M);
    for (int s = 0; s < NSTEP; ++s) {
        k_invblk<double><<<BB, 256, 0, stream>>>(M, Bb, s * KB);
        k_piv_mfma<<<dim3(8, BB), 256, 0, stream>>>(M, Bb, s);
        k_upd2<<<dim3(14, BB), 256, 0, stream>>>(M, Bb, s);
    }
    k_dgloss<double><<<BB * NN / 256, 256, 0, stream>>>(M, Rf, rlab, rmask, Dg, lossp);
    k_lossfin<<<1, 128, 0, stream>>>(lossp, lossout);
    k_d2<double><<<dim3(BB, 8, 8), 256, 0, stream>>>(M, Dg, adj, mask, dmat, ATh, ATl);
    k_cvt_x<<<dim3(BB, 8, 12), 256, 0, stream>>>(x, XTh, XTl);   // overwrites M region
    k_ctx3<<<dim3(BB, 4, 6), 256, 0, stream>>>(ATh, ATl, XTh, XTl, ctx);
}

extern "C" void kernel_launch(void* const* d_in, const int* in_sizes, int n_in,
                              void* d_out, int out_size, void* d_ws, size_t ws_size,
                              hipStream_t stream) {
    const float* x    = (const float*)d_in[0];
    const float* adj  = (const float*)d_in[1];
    const float* mask = (const float*)d_in[2];
    const float* rlab = (const float*)d_in[3];
    const int*   rmask= (const int*)d_in[4];
    const float* w    = (const float*)d_in[5];
    const float* br   = (const float*)d_in[6];
    float* out = (float*)d_out;
    float* ctx = out;
    float* dmat = out + (size_t)BB * NN * DD;
    float* lossout = dmat + (size_t)BB * NN * NN;
    char* ws = (char*)d_ws;

    size_t base = (size_t)BB * NN * NN * 8 + (size_t)BB * NN * KB * 8 + (size_t)BB * KB * KB * 8
                + (size_t)BB * 4 * NN * 8 + (size_t)BB * NN * 4 + (size_t)BB * NN * 8 + 4096;
    size_t need_new = base + (size_t)BB * NN * NN * 4;
    if (ws_size >= need_new)
        run_new(x, adj, mask, rlab, rmask, w, br, ctx, dmat, lossout, ws, stream);
    else if (ws_size >= base)
        run_old<double>(x, adj, mask, rlab, rmask, w, br, ctx, dmat, lossout, ws, stream);
    else
        run_old<float>(x, adj, mask, rlab, rmask, w, br, ctx, dmat, lossout, ws, stream);
}